// Round 1
// baseline (1200.016 us; speedup 1.0000x reference)
//
#include <hip/hip_runtime.h>
#include <cmath>

// ---------------- octonion tables: indexed [c][r] ----------------
__constant__ int c_IDX[64] = {
  0,1,2,3,4,5,6,7,
  1,0,3,2,5,4,7,6,
  2,3,0,1,6,7,4,5,
  3,2,1,0,7,6,5,4,
  4,5,6,7,0,1,2,3,
  5,4,7,6,1,0,3,2,
  6,7,4,5,2,3,0,1,
  7,6,5,4,3,2,1,0};
__constant__ float c_SIGN[64] = {
  1,1,1,1,1,1,1,1,
  1,-1,1,-1,1,-1,-1,1,
  1,-1,-1,1,1,1,-1,-1,
  1,1,-1,-1,1,-1,1,-1,
  1,-1,-1,-1,-1,1,1,1,
  1,1,-1,1,-1,-1,-1,1,
  1,1,1,-1,-1,1,-1,-1,
  1,-1,1,1,-1,-1,1,-1};

// hamilton[row*256+col], row=r*32+i, col=c*32+o:
//   = SIGN[c][r] * weight[i*256 + IDX[c][r]*32 + o]
__global__ __launch_bounds__(256) void ham_kernel(const float* __restrict__ weight,
                                                  float* __restrict__ ham) {
  int idx = blockIdx.x * 256 + threadIdx.x;   // 65536 total
  int row = idx >> 8, col = idx & 255;
  int r = row >> 5, i = row & 31, c = col >> 5, o = col & 31;
  ham[idx] = c_SIGN[c * 8 + r] * weight[i * 256 + c_IDX[c * 8 + r] * 32 + o];
}

// ---------------- CSR build ----------------
__global__ __launch_bounds__(256) void hist_kernel(const int* __restrict__ dst,
                                                   int* __restrict__ cnt, int E) {
  int i = blockIdx.x * 256 + threadIdx.x;
  if (i < E) atomicAdd(&cnt[dst[i]], 1);
}

// single-block exclusive scan over N counters -> off, cursor
__global__ __launch_bounds__(1024) void scan_kernel(const int* __restrict__ cnt,
                                                    int* __restrict__ off,
                                                    int* __restrict__ cursor, int N) {
  __shared__ int wsum[16];
  __shared__ int wbase[17];
  const int tid = threadIdx.x;
  const int lane = tid & 63, wid = tid >> 6;
  int carry = 0;  // uniform across threads
  for (int base = 0; base < N; base += 1024) {
    int i = base + tid;
    int v = (i < N) ? cnt[i] : 0;
    int incl = v;
    #pragma unroll
    for (int d = 1; d < 64; d <<= 1) {
      int u = __shfl_up(incl, d);
      if (lane >= d) incl += u;
    }
    if (lane == 63) wsum[wid] = incl;
    __syncthreads();
    if (tid == 0) {
      int s = 0;
      #pragma unroll
      for (int w = 0; w < 16; w++) { wbase[w] = s; s += wsum[w]; }
      wbase[16] = s;
    }
    __syncthreads();
    int excl = carry + wbase[wid] + incl - v;
    if (i < N) { off[i] = excl; cursor[i] = excl; }
    carry += wbase[16];
    __syncthreads();
  }
}

__global__ __launch_bounds__(256) void scatter_kernel(const int* __restrict__ src,
                                                      const int* __restrict__ dst,
                                                      const float* __restrict__ w,
                                                      int* __restrict__ cursor,
                                                      int2* __restrict__ edges, int E) {
  int i = blockIdx.x * 256 + threadIdx.x;
  if (i < E) {
    int d = dst[i];
    int pos = atomicAdd(&cursor[d], 1);
    edges[pos] = make_int2(src[i], __float_as_int(w[i]));
  }
}

// ---------------- gather-aggregate: agg[d] = sum_e w_e * x[src_e] ----------------
// one wave per dst row; 4 rows per 256-thread block
__global__ __launch_bounds__(256) void gather_kernel(const float4* __restrict__ x4,
                                                     const int2* __restrict__ edges,
                                                     const int* __restrict__ off,
                                                     const int* __restrict__ cnt,
                                                     float4* __restrict__ agg4, int N) {
  int d = blockIdx.x * 4 + (threadIdx.x >> 6);
  if (d >= N) return;
  int lane = threadIdx.x & 63;
  int start = off[d], n = cnt[d];
  float4 acc = make_float4(0.f, 0.f, 0.f, 0.f);
  int j = 0;
  for (; j + 1 < n; j += 2) {  // unroll-2 so loads overlap
    int2 e0 = edges[start + j];
    int2 e1 = edges[start + j + 1];
    float4 v0 = x4[(size_t)e0.x * 64 + lane];
    float4 v1 = x4[(size_t)e1.x * 64 + lane];
    float w0 = __int_as_float(e0.y), w1 = __int_as_float(e1.y);
    acc.x = fmaf(w0, v0.x, acc.x); acc.y = fmaf(w0, v0.y, acc.y);
    acc.z = fmaf(w0, v0.z, acc.z); acc.w = fmaf(w0, v0.w, acc.w);
    acc.x = fmaf(w1, v1.x, acc.x); acc.y = fmaf(w1, v1.y, acc.y);
    acc.z = fmaf(w1, v1.z, acc.z); acc.w = fmaf(w1, v1.w, acc.w);
  }
  if (j < n) {
    int2 e0 = edges[start + j];
    float4 v0 = x4[(size_t)e0.x * 64 + lane];
    float w0 = __int_as_float(e0.y);
    acc.x = fmaf(w0, v0.x, acc.x); acc.y = fmaf(w0, v0.y, acc.y);
    acc.z = fmaf(w0, v0.z, acc.z); acc.w = fmaf(w0, v0.w, acc.w);
  }
  agg4[(size_t)d * 64 + lane] = acc;
}

// ---------------- fp32 GEMM: out = agg[N x 256] @ ham[256 x 256] ----------------
// BM=64 rows, BN=256 (full), BK=32; 256 threads; 8x8 micro-tile per thread
#define BM 64
#define BK 32
__global__ __launch_bounds__(256) void gemm_kernel(const float* __restrict__ agg,
                                                   const float* __restrict__ ham,
                                                   float* __restrict__ out, int N) {
  __shared__ float As[BK][68];    // transposed: As[k][r], r-padded to 68
  __shared__ float Bs[BK][256];
  const int tid = threadIdx.x;
  const int tx = tid & 31;        // col group (8 cols)
  const int ty = tid >> 5;        // row group (8 rows)
  const int row0 = blockIdx.x * BM;
  const int r = tid & 63, h = tid >> 6;

  float acc[8][8];
  #pragma unroll
  for (int i = 0; i < 8; i++) {
    #pragma unroll
    for (int j = 0; j < 8; j++) acc[i][j] = 0.f;
  }

  const float4* agg4 = (const float4*)agg;
  const float4* ham4 = (const float4*)ham;
  const int grow = row0 + r;

  for (int k0 = 0; k0 < 256; k0 += BK) {
    // stage A (64 rows x 32 k), transposed into As[k][r]
    #pragma unroll
    for (int ff = 0; ff < 2; ff++) {
      int f = h + ff * 4;   // float4 index within the 32-k slab
      float4 v = make_float4(0.f, 0.f, 0.f, 0.f);
      if (grow < N) v = agg4[(size_t)grow * 64 + (k0 >> 2) + f];
      As[f * 4 + 0][r] = v.x; As[f * 4 + 1][r] = v.y;
      As[f * 4 + 2][r] = v.z; As[f * 4 + 3][r] = v.w;
    }
    // stage B (32 k x 256 cols), row-major
    #pragma unroll
    for (int i = 0; i < 8; i++) {
      int idx = tid + i * 256;           // 0..2047
      int kr = idx >> 6, c4 = idx & 63;
      float4 v = ham4[(size_t)(k0 + kr) * 64 + c4];
      *(float4*)&Bs[kr][c4 * 4] = v;
    }
    __syncthreads();

    #pragma unroll 4
    for (int k = 0; k < BK; k++) {
      float a[8], b[8];
      *(float4*)&a[0] = *(const float4*)&As[k][ty * 8];
      *(float4*)&a[4] = *(const float4*)&As[k][ty * 8 + 4];
      *(float4*)&b[0] = *(const float4*)&Bs[k][tx * 8];
      *(float4*)&b[4] = *(const float4*)&Bs[k][tx * 8 + 4];
      #pragma unroll
      for (int i = 0; i < 8; i++) {
        #pragma unroll
        for (int j = 0; j < 8; j++) acc[i][j] = fmaf(a[i], b[j], acc[i][j]);
      }
    }
    __syncthreads();
  }

  float4* out4 = (float4*)out;
  #pragma unroll
  for (int i = 0; i < 8; i++) {
    int gr = row0 + ty * 8 + i;
    if (gr < N) {
      float4 v0 = make_float4(acc[i][0], acc[i][1], acc[i][2], acc[i][3]);
      float4 v1 = make_float4(acc[i][4], acc[i][5], acc[i][6], acc[i][7]);
      out4[(size_t)gr * 64 + tx * 2]     = v0;
      out4[(size_t)gr * 64 + tx * 2 + 1] = v1;
    }
  }
}

// ---------------- BN stats: per-column sum & sumsq ----------------
__global__ __launch_bounds__(256) void stats_kernel(const float* __restrict__ pre,
                                                    float* __restrict__ bnsum, int N) {
  int c = threadIdx.x;
  int r0 = blockIdx.x * 64;
  int r1 = r0 + 64; if (r1 > N) r1 = N;
  float s = 0.f, s2 = 0.f;
  for (int row = r0; row < r1; row++) {
    float v = pre[(size_t)row * 256 + c];
    s += v; s2 = fmaf(v, v, s2);
  }
  atomicAdd(&bnsum[c], s);
  atomicAdd(&bnsum[256 + c], s2);
}

__global__ void bnscale_kernel(const float* __restrict__ bnsum,
                               const float* __restrict__ gamma,
                               const float* __restrict__ beta,
                               float* __restrict__ bnsc, int N) {
  int c = threadIdx.x;  // 256
  float invN = 1.f / (float)N;
  float mean = bnsum[c] * invN;
  float var  = bnsum[256 + c] * invN - mean * mean;
  float sc = rsqrtf(var + 1e-5f) * gamma[c];
  bnsc[c] = sc;
  bnsc[256 + c] = beta[c] - mean * sc;
}

__global__ __launch_bounds__(256) void final_kernel(float* __restrict__ out,
                                                    const float* __restrict__ bnsc,
                                                    size_t total4) {
  size_t idx = (size_t)blockIdx.x * 256 + threadIdx.x;
  size_t stride = (size_t)gridDim.x * 256;
  float4* out4 = (float4*)out;
  for (size_t i = idx; i < total4; i += stride) {
    float4 v = out4[i];
    int c0 = (int)((i * 4) & 255);
    v.x = tanhf(fmaf(v.x, bnsc[c0 + 0], bnsc[256 + c0 + 0]));
    v.y = tanhf(fmaf(v.y, bnsc[c0 + 1], bnsc[256 + c0 + 1]));
    v.z = tanhf(fmaf(v.z, bnsc[c0 + 2], bnsc[256 + c0 + 2]));
    v.w = tanhf(fmaf(v.w, bnsc[c0 + 3], bnsc[256 + c0 + 3]));
    out4[i] = v;
  }
}

// ---------------- launch ----------------
extern "C" void kernel_launch(void* const* d_in, const int* in_sizes, int n_in,
                              void* d_out, int out_size, void* d_ws, size_t ws_size,
                              hipStream_t stream) {
  const float* x      = (const float*)d_in[0];
  const float* weight = (const float*)d_in[1];
  const float* gamma  = (const float*)d_in[2];
  const float* beta   = (const float*)d_in[3];
  const float* ew     = (const float*)d_in[4];
  const int*   esrc   = (const int*)d_in[5];
  const int*   edst   = (const int*)d_in[6];
  const int N = in_sizes[0] / 256;
  const int E = in_sizes[4];
  float* out = (float*)d_out;

  char* p = (char*)d_ws;
  auto alloc = [&](size_t bytes) {
    char* q = p;
    p += (bytes + 255) & ~(size_t)255;
    return q;
  };
  float* ham    = (float*)alloc(256 * 256 * 4);
  int*   cnt    = (int*)alloc((size_t)N * 4);
  int*   off    = (int*)alloc((size_t)N * 4);
  int*   cursor = (int*)alloc((size_t)N * 4);
  int2*  edges  = (int2*)alloc((size_t)E * 8);
  float* agg    = (float*)alloc((size_t)N * 256 * 4);
  float* bnsum  = (float*)alloc(512 * 4);
  float* bnsc   = (float*)alloc(512 * 4);

  hipMemsetAsync(cnt, 0, (size_t)N * 4, stream);
  hipMemsetAsync(bnsum, 0, 512 * 4, stream);

  ham_kernel<<<256, 256, 0, stream>>>(weight, ham);
  hist_kernel<<<(E + 255) / 256, 256, 0, stream>>>(edst, cnt, E);
  scan_kernel<<<1, 1024, 0, stream>>>(cnt, off, cursor, N);
  scatter_kernel<<<(E + 255) / 256, 256, 0, stream>>>(esrc, edst, ew, cursor, edges, E);
  gather_kernel<<<(N + 3) / 4, 256, 0, stream>>>((const float4*)x, edges, off, cnt,
                                                 (float4*)agg, N);
  gemm_kernel<<<(N + BM - 1) / BM, 256, 0, stream>>>(agg, ham, out, N);
  stats_kernel<<<(N + 63) / 64, 256, 0, stream>>>(out, bnsum, N);
  bnscale_kernel<<<1, 256, 0, stream>>>(bnsum, gamma, beta, bnsc, N);
  final_kernel<<<2048, 256, 0, stream>>>(out, bnsc, (size_t)N * 64);
}

// Round 2
// 918.751 us; speedup vs baseline: 1.3061x; 1.3061x over previous
//
#include <hip/hip_runtime.h>
#include <cmath>

// ---------------- octonion tables: indexed [c][r] ----------------
__constant__ int c_IDX[64] = {
  0,1,2,3,4,5,6,7,
  1,0,3,2,5,4,7,6,
  2,3,0,1,6,7,4,5,
  3,2,1,0,7,6,5,4,
  4,5,6,7,0,1,2,3,
  5,4,7,6,1,0,3,2,
  6,7,4,5,2,3,0,1,
  7,6,5,4,3,2,1,0};
__constant__ float c_SIGN[64] = {
  1,1,1,1,1,1,1,1,
  1,-1,1,-1,1,-1,-1,1,
  1,-1,-1,1,1,1,-1,-1,
  1,1,-1,-1,1,-1,1,-1,
  1,-1,-1,-1,-1,1,1,1,
  1,1,-1,1,-1,-1,-1,1,
  1,1,1,-1,-1,1,-1,-1,
  1,-1,1,1,-1,-1,1,-1};

__global__ __launch_bounds__(256) void ham_kernel(const float* __restrict__ weight,
                                                  float* __restrict__ ham) {
  int idx = blockIdx.x * 256 + threadIdx.x;   // 65536 total
  int row = idx >> 8, col = idx & 255;
  int r = row >> 5, i = row & 31, c = col >> 5, o = col & 31;
  ham[idx] = c_SIGN[c * 8 + r] * weight[i * 256 + c_IDX[c * 8 + r] * 32 + o];
}

// ---------------- x -> packed bf16 (RNE) ----------------
__device__ inline unsigned bfpack(float lo, float hi) {
  unsigned ul = __float_as_uint(lo), uh = __float_as_uint(hi);
  ul = (ul + 0x7fffu + ((ul >> 16) & 1u)) >> 16;
  uh = (uh + 0x7fffu + ((uh >> 16) & 1u)) & 0xffff0000u;
  return ul | uh;
}

__global__ __launch_bounds__(256) void cvt_kernel(const float4* __restrict__ x4,
                                                  uint2* __restrict__ xh, size_t n4) {
  size_t idx = (size_t)blockIdx.x * 256 + threadIdx.x;
  size_t stride = (size_t)gridDim.x * 256;
  for (size_t i = idx; i < n4; i += stride) {
    float4 v = x4[i];
    xh[i] = make_uint2(bfpack(v.x, v.y), bfpack(v.z, v.w));
  }
}

// ---------------- CSR build ----------------
__global__ __launch_bounds__(256) void hist_kernel(const int* __restrict__ dst,
                                                   int* __restrict__ cnt, int E) {
  int i = blockIdx.x * 256 + threadIdx.x;
  if (i < E) atomicAdd(&cnt[dst[i]], 1);
}

// hierarchical scan: 2048 elems per 256-thread block
__global__ __launch_bounds__(256) void scan_partial(const int* __restrict__ cnt,
                                                    int* __restrict__ bsum, int N) {
  __shared__ int ws_[4];
  int b = blockIdx.x, tid = threadIdx.x;
  int base = b * 2048 + tid * 8;
  int s = 0;
  #pragma unroll
  for (int k = 0; k < 8; k++) { int i = base + k; if (i < N) s += cnt[i]; }
  #pragma unroll
  for (int d = 1; d < 64; d <<= 1) s += __shfl_xor(s, d);
  if ((tid & 63) == 0) ws_[tid >> 6] = s;
  __syncthreads();
  if (tid == 0) bsum[b] = ws_[0] + ws_[1] + ws_[2] + ws_[3];
}

__global__ void scan_bases(int* __restrict__ bsum, int nb) {
  int lane = threadIdx.x;   // 64 threads
  int carry = 0;
  for (int base = 0; base < nb; base += 64) {
    int i = base + lane;
    int v = (i < nb) ? bsum[i] : 0;
    int incl = v;
    #pragma unroll
    for (int d = 1; d < 64; d <<= 1) { int u = __shfl_up(incl, d); if (lane >= d) incl += u; }
    if (i < nb) bsum[i] = carry + incl - v;
    carry += __shfl(incl, 63);
  }
}

__global__ __launch_bounds__(256) void scan_final(const int* __restrict__ cnt,
                                                  const int* __restrict__ bsum,
                                                  int* __restrict__ off,
                                                  int* __restrict__ cursor, int N) {
  __shared__ int wsum[4];
  __shared__ int wbase[4];
  int b = blockIdx.x, tid = threadIdx.x, lane = tid & 63, wid = tid >> 6;
  int base = b * 2048 + tid * 8;
  int v[8]; int s = 0;
  #pragma unroll
  for (int k = 0; k < 8; k++) { int i = base + k; v[k] = (i < N) ? cnt[i] : 0; s += v[k]; }
  int incl = s;
  #pragma unroll
  for (int d = 1; d < 64; d <<= 1) { int u = __shfl_up(incl, d); if (lane >= d) incl += u; }
  if (lane == 63) wsum[wid] = incl;
  __syncthreads();
  if (tid == 0) { int t = 0; for (int w = 0; w < 4; w++) { wbase[w] = t; t += wsum[w]; } }
  __syncthreads();
  int excl = bsum[b] + wbase[wid] + incl - s;
  #pragma unroll
  for (int k = 0; k < 8; k++) {
    int i = base + k;
    if (i < N) { off[i] = excl; cursor[i] = excl; }
    excl += v[k];
  }
}

__global__ __launch_bounds__(256) void scatter_kernel(const int* __restrict__ src,
                                                      const int* __restrict__ dst,
                                                      const float* __restrict__ w,
                                                      int* __restrict__ cursor,
                                                      int2* __restrict__ edges, int E) {
  int i = blockIdx.x * 256 + threadIdx.x;
  if (i < E) {
    int d = dst[i];
    int pos = atomicAdd(&cursor[d], 1);
    edges[pos] = make_int2(src[i], __float_as_int(w[i]));
  }
}

// ---------------- gather-aggregate (bf16 rows, fp32 accum) ----------------
__device__ inline void acc_bf16(float4& acc, uint2 v, float w) {
  acc.x = fmaf(w, __uint_as_float(v.x << 16), acc.x);
  acc.y = fmaf(w, __uint_as_float(v.x & 0xffff0000u), acc.y);
  acc.z = fmaf(w, __uint_as_float(v.y << 16), acc.z);
  acc.w = fmaf(w, __uint_as_float(v.y & 0xffff0000u), acc.w);
}

__global__ __launch_bounds__(256) void gather_kernel(const uint2* __restrict__ xh,
                                                     const int2* __restrict__ edges,
                                                     const int* __restrict__ off,
                                                     const int* __restrict__ cnt,
                                                     float4* __restrict__ agg4, int N) {
  int d = blockIdx.x * 4 + (threadIdx.x >> 6);
  if (d >= N) return;
  int lane = threadIdx.x & 63;
  int start = off[d], n = cnt[d];
  float4 acc = make_float4(0.f, 0.f, 0.f, 0.f);
  int j = 0;
  for (; j + 3 < n; j += 4) {
    int2 e0 = edges[start + j];
    int2 e1 = edges[start + j + 1];
    int2 e2 = edges[start + j + 2];
    int2 e3 = edges[start + j + 3];
    uint2 v0 = xh[(size_t)e0.x * 64 + lane];
    uint2 v1 = xh[(size_t)e1.x * 64 + lane];
    uint2 v2 = xh[(size_t)e2.x * 64 + lane];
    uint2 v3 = xh[(size_t)e3.x * 64 + lane];
    acc_bf16(acc, v0, __int_as_float(e0.y));
    acc_bf16(acc, v1, __int_as_float(e1.y));
    acc_bf16(acc, v2, __int_as_float(e2.y));
    acc_bf16(acc, v3, __int_as_float(e3.y));
  }
  for (; j < n; j++) {
    int2 e0 = edges[start + j];
    uint2 v0 = xh[(size_t)e0.x * 64 + lane];
    acc_bf16(acc, v0, __int_as_float(e0.y));
  }
  agg4[(size_t)d * 64 + lane] = acc;
}

// ---------------- fp32 GEMM: out = agg[N x 256] @ ham[256 x 256] (in-place safe) ----
#define BM 64
#define BK 32
__global__ __launch_bounds__(256) void gemm_kernel(const float* __restrict__ agg,
                                                   const float* __restrict__ ham,
                                                   float* __restrict__ out, int N) {
  __shared__ float As[BK][68];
  __shared__ float Bs[BK][256];
  const int tid = threadIdx.x;
  const int tx = tid & 31;
  const int ty = tid >> 5;
  const int row0 = blockIdx.x * BM;
  const int r = tid & 63, h = tid >> 6;

  float acc[8][8];
  #pragma unroll
  for (int i = 0; i < 8; i++)
    #pragma unroll
    for (int j = 0; j < 8; j++) acc[i][j] = 0.f;

  const float4* agg4 = (const float4*)agg;
  const float4* ham4 = (const float4*)ham;
  const int grow = row0 + r;

  for (int k0 = 0; k0 < 256; k0 += BK) {
    #pragma unroll
    for (int ff = 0; ff < 2; ff++) {
      int f = h + ff * 4;
      float4 v = make_float4(0.f, 0.f, 0.f, 0.f);
      if (grow < N) v = agg4[(size_t)grow * 64 + (k0 >> 2) + f];
      As[f * 4 + 0][r] = v.x; As[f * 4 + 1][r] = v.y;
      As[f * 4 + 2][r] = v.z; As[f * 4 + 3][r] = v.w;
    }
    #pragma unroll
    for (int i = 0; i < 8; i++) {
      int idx = tid + i * 256;
      int kr = idx >> 6, c4 = idx & 63;
      float4 v = ham4[(size_t)(k0 + kr) * 64 + c4];
      *(float4*)&Bs[kr][c4 * 4] = v;
    }
    __syncthreads();

    #pragma unroll 4
    for (int k = 0; k < BK; k++) {
      float a[8], b[8];
      *(float4*)&a[0] = *(const float4*)&As[k][ty * 8];
      *(float4*)&a[4] = *(const float4*)&As[k][ty * 8 + 4];
      *(float4*)&b[0] = *(const float4*)&Bs[k][tx * 8];
      *(float4*)&b[4] = *(const float4*)&Bs[k][tx * 8 + 4];
      #pragma unroll
      for (int i = 0; i < 8; i++)
        #pragma unroll
        for (int j = 0; j < 8; j++) acc[i][j] = fmaf(a[i], b[j], acc[i][j]);
    }
    __syncthreads();
  }

  float4* out4 = (float4*)out;
  #pragma unroll
  for (int i = 0; i < 8; i++) {
    int gr = row0 + ty * 8 + i;
    if (gr < N) {
      out4[(size_t)gr * 64 + tx * 2]     = make_float4(acc[i][0], acc[i][1], acc[i][2], acc[i][3]);
      out4[(size_t)gr * 64 + tx * 2 + 1] = make_float4(acc[i][4], acc[i][5], acc[i][6], acc[i][7]);
    }
  }
}

// ---------------- BN stats ----------------
__global__ __launch_bounds__(256) void stats_kernel(const float* __restrict__ pre,
                                                    float* __restrict__ bnsum, int N) {
  int c = threadIdx.x;
  int r0 = blockIdx.x * 64;
  int r1 = r0 + 64; if (r1 > N) r1 = N;
  float s = 0.f, s2 = 0.f;
  for (int row = r0; row < r1; row++) {
    float v = pre[(size_t)row * 256 + c];
    s += v; s2 = fmaf(v, v, s2);
  }
  atomicAdd(&bnsum[c], s);
  atomicAdd(&bnsum[256 + c], s2);
}

__global__ void bnscale_kernel(const float* __restrict__ bnsum,
                               const float* __restrict__ gamma,
                               const float* __restrict__ beta,
                               float* __restrict__ bnsc, int N) {
  int c = threadIdx.x;
  float invN = 1.f / (float)N;
  float mean = bnsum[c] * invN;
  float var  = bnsum[256 + c] * invN - mean * mean;
  float sc = rsqrtf(var + 1e-5f) * gamma[c];
  bnsc[c] = sc;
  bnsc[256 + c] = beta[c] - mean * sc;
}

__global__ __launch_bounds__(256) void final_kernel(float* __restrict__ out,
                                                    const float* __restrict__ bnsc,
                                                    size_t total4) {
  size_t idx = (size_t)blockIdx.x * 256 + threadIdx.x;
  size_t stride = (size_t)gridDim.x * 256;
  float4* out4 = (float4*)out;
  for (size_t i = idx; i < total4; i += stride) {
    float4 v = out4[i];
    int c0 = (int)((i * 4) & 255);
    v.x = tanhf(fmaf(v.x, bnsc[c0 + 0], bnsc[256 + c0 + 0]));
    v.y = tanhf(fmaf(v.y, bnsc[c0 + 1], bnsc[256 + c0 + 1]));
    v.z = tanhf(fmaf(v.z, bnsc[c0 + 2], bnsc[256 + c0 + 2]));
    v.w = tanhf(fmaf(v.w, bnsc[c0 + 3], bnsc[256 + c0 + 3]));
    out4[i] = v;
  }
}

// ---------------- launch ----------------
extern "C" void kernel_launch(void* const* d_in, const int* in_sizes, int n_in,
                              void* d_out, int out_size, void* d_ws, size_t ws_size,
                              hipStream_t stream) {
  const float* x      = (const float*)d_in[0];
  const float* weight = (const float*)d_in[1];
  const float* gamma  = (const float*)d_in[2];
  const float* beta   = (const float*)d_in[3];
  const float* ew     = (const float*)d_in[4];
  const int*   esrc   = (const int*)d_in[5];
  const int*   edst   = (const int*)d_in[6];
  const int N = in_sizes[0] / 256;
  const int E = in_sizes[4];
  float* out = (float*)d_out;

  char* p = (char*)d_ws;
  auto alloc = [&](size_t bytes) {
    char* q = p;
    p += (bytes + 255) & ~(size_t)255;
    return q;
  };
  float* ham    = (float*)alloc(256 * 256 * 4);
  int*   cnt    = (int*)alloc((size_t)N * 4);
  int*   off    = (int*)alloc((size_t)N * 4);
  int*   cursor = (int*)alloc((size_t)N * 4);
  int2*  edges  = (int2*)alloc((size_t)E * 8);
  uint2* xh     = (uint2*)alloc((size_t)N * 256 * 2);   // packed bf16 x
  float* bnsum  = (float*)alloc(512 * 4);
  float* bnsc   = (float*)alloc(512 * 4);
  int*   bsum   = (int*)alloc(4096 * 4);
  float* agg    = out;   // alias: gemm is in-place-safe (reads its rows before writing)

  hipMemsetAsync(cnt, 0, (size_t)N * 4, stream);
  hipMemsetAsync(bnsum, 0, 512 * 4, stream);

  const int nb = (N + 2047) / 2048;

  ham_kernel<<<256, 256, 0, stream>>>(weight, ham);
  cvt_kernel<<<2048, 256, 0, stream>>>((const float4*)x, xh, (size_t)N * 64);
  hist_kernel<<<(E + 255) / 256, 256, 0, stream>>>(edst, cnt, E);
  scan_partial<<<nb, 256, 0, stream>>>(cnt, bsum, N);
  scan_bases<<<1, 64, 0, stream>>>(bsum, nb);
  scan_final<<<nb, 256, 0, stream>>>(cnt, bsum, off, cursor, N);
  scatter_kernel<<<(E + 255) / 256, 256, 0, stream>>>(esrc, edst, ew, cursor, edges, E);
  gather_kernel<<<(N + 3) / 4, 256, 0, stream>>>(xh, edges, off, cnt, (float4*)agg, N);
  gemm_kernel<<<(N + BM - 1) / BM, 256, 0, stream>>>(agg, ham, out, N);
  stats_kernel<<<(N + 63) / 64, 256, 0, stream>>>(out, bnsum, N);
  bnscale_kernel<<<1, 256, 0, stream>>>(bnsum, gamma, beta, bnsc, N);
  final_kernel<<<2048, 256, 0, stream>>>(out, bnsc, (size_t)N * 64);
}

// Round 3
// 700.902 us; speedup vs baseline: 1.7121x; 1.3108x over previous
//
#include <hip/hip_runtime.h>
#include <cmath>

#define NB 512        // dst-range bins
#define CHUNK 8192    // edges per block in binning kernels

// ---------------- octonion tables: indexed [c][r] ----------------
__constant__ int c_IDX[64] = {
  0,1,2,3,4,5,6,7,
  1,0,3,2,5,4,7,6,
  2,3,0,1,6,7,4,5,
  3,2,1,0,7,6,5,4,
  4,5,6,7,0,1,2,3,
  5,4,7,6,1,0,3,2,
  6,7,4,5,2,3,0,1,
  7,6,5,4,3,2,1,0};
__constant__ float c_SIGN[64] = {
  1,1,1,1,1,1,1,1,
  1,-1,1,-1,1,-1,-1,1,
  1,-1,-1,1,1,1,-1,-1,
  1,1,-1,-1,1,-1,1,-1,
  1,-1,-1,-1,-1,1,1,1,
  1,1,-1,1,-1,-1,-1,1,
  1,1,1,-1,-1,1,-1,-1,
  1,-1,1,1,-1,-1,1,-1};

__global__ __launch_bounds__(256) void ham_kernel(const float* __restrict__ weight,
                                                  float* __restrict__ ham) {
  int idx = blockIdx.x * 256 + threadIdx.x;   // 65536 total
  int row = idx >> 8, col = idx & 255;
  int r = row >> 5, i = row & 31, c = col >> 5, o = col & 31;
  ham[idx] = c_SIGN[c * 8 + r] * weight[i * 256 + c_IDX[c * 8 + r] * 32 + o];
}

// ---------------- x -> packed bf16 (RNE) ----------------
__device__ inline unsigned bfpack(float lo, float hi) {
  unsigned ul = __float_as_uint(lo), uh = __float_as_uint(hi);
  ul = (ul + 0x7fffu + ((ul >> 16) & 1u)) >> 16;
  uh = (uh + 0x7fffu + ((uh >> 16) & 1u)) & 0xffff0000u;
  return ul | uh;
}

__global__ __launch_bounds__(256) void cvt_kernel(const float4* __restrict__ x4,
                                                  uint2* __restrict__ xh, size_t n4) {
  size_t idx = (size_t)blockIdx.x * 256 + threadIdx.x;
  size_t stride = (size_t)gridDim.x * 256;
  for (size_t i = idx; i < n4; i += stride) {
    float4 v = x4[i];
    xh[i] = make_uint2(bfpack(v.x, v.y), bfpack(v.z, v.w));
  }
}

// ---------------- bin histogram (LDS-aggregated) ----------------
__global__ __launch_bounds__(256) void binhist_kernel(const int* __restrict__ dst,
                                                      int* __restrict__ binTot,
                                                      int E, int N) {
  __shared__ int h[NB];
  int tid = threadIdx.x;
  for (int i = tid; i < NB; i += 256) h[i] = 0;
  __syncthreads();
  int base = blockIdx.x * CHUNK;
  int end = base + CHUNK; if (end > E) end = E;
  for (int i = base + tid; i < end; i += 256)
    atomicAdd(&h[(int)((long long)dst[i] * NB / N)], 1);
  __syncthreads();
  for (int i = tid; i < NB; i += 256)
    if (h[i]) atomicAdd(&binTot[i], h[i]);
}

// single block, NB=512 threads: exclusive scan -> binStart, binCursor
__global__ __launch_bounds__(512) void binscan_kernel(const int* __restrict__ binTot,
                                                      int* __restrict__ binStart,
                                                      int* __restrict__ binCursor, int E) {
  __shared__ int wsum[8], wbase[8];
  int tid = threadIdx.x, lane = tid & 63, wid = tid >> 6;
  int v = binTot[tid];
  int incl = v;
  #pragma unroll
  for (int d = 1; d < 64; d <<= 1) { int u = __shfl_up(incl, d); if (lane >= d) incl += u; }
  if (lane == 63) wsum[wid] = incl;
  __syncthreads();
  if (tid == 0) { int s = 0; for (int w = 0; w < 8; w++) { wbase[w] = s; s += wsum[w]; } }
  __syncthreads();
  int excl = wbase[wid] + incl - v;
  binStart[tid] = excl;
  binCursor[tid] = excl;
  if (tid == NB - 1) binStart[NB] = E;
}

// ---------------- pass 1: scatter edges into dst-range bins ----------------
__global__ __launch_bounds__(256) void bin_scatter(const int* __restrict__ src,
                                                   const int* __restrict__ dst,
                                                   const float* __restrict__ w,
                                                   int* __restrict__ binCursor,
                                                   int2* __restrict__ bb_sw,
                                                   int* __restrict__ bb_d, int E, int N) {
  __shared__ int hist[NB];
  __shared__ int lcur[NB];
  int tid = threadIdx.x;
  int base = blockIdx.x * CHUNK;
  int end = base + CHUNK; if (end > E) end = E;
  for (int i = tid; i < NB; i += 256) hist[i] = 0;
  __syncthreads();
  for (int i = base + tid; i < end; i += 256)
    atomicAdd(&hist[(int)((long long)dst[i] * NB / N)], 1);
  __syncthreads();
  for (int i = tid; i < NB; i += 256) {
    int h = hist[i];
    lcur[i] = h ? atomicAdd(&binCursor[i], h) : 0;
  }
  __syncthreads();
  for (int i = base + tid; i < end; i += 256) {
    int d = dst[i];
    int b = (int)((long long)d * NB / N);
    int pos = atomicAdd(&lcur[b], 1);
    bb_sw[pos] = make_int2(src[i], __float_as_int(w[i]));
    bb_d[pos] = d;
  }
}

// ---------------- pass 2: per-bin local CSR + exact placement ----------------
// one block per bin; also writes global off/cnt for the gather
__global__ __launch_bounds__(256) void bin_place(const int2* __restrict__ bb_sw,
                                                 const int* __restrict__ bb_d,
                                                 const int* __restrict__ binStart,
                                                 int* __restrict__ off,
                                                 int* __restrict__ cnt,
                                                 int2* __restrict__ edges, int N) {
  __shared__ int lcnt[208];
  __shared__ int loff[208];
  int b = blockIdx.x, tid = threadIdx.x;
  int d0 = (int)(((long long)b * N + NB - 1) / NB);
  int d1 = (int)(((long long)(b + 1) * N + NB - 1) / NB);
  if (d1 > N) d1 = N;
  int nd = d1 - d0;
  int e0 = binStart[b], e1 = binStart[b + 1];
  for (int i = tid; i < nd; i += 256) lcnt[i] = 0;
  __syncthreads();
  for (int i = e0 + tid; i < e1; i += 256) atomicAdd(&lcnt[bb_d[i] - d0], 1);
  __syncthreads();
  if (tid == 0) {
    int s = e0;
    for (int i = 0; i < nd; i++) { loff[i] = s; s += lcnt[i]; }
  }
  __syncthreads();
  for (int i = tid; i < nd; i += 256) {
    off[d0 + i] = loff[i];
    cnt[d0 + i] = lcnt[i];
  }
  __syncthreads();
  for (int i = tid; i < nd; i += 256) lcnt[i] = loff[i];  // reuse as cursors
  __syncthreads();
  for (int i = e0 + tid; i < e1; i += 256) {
    int d = bb_d[i];
    int pos = atomicAdd(&lcnt[d - d0], 1);
    edges[pos] = bb_sw[i];
  }
}

// ---------------- gather-aggregate (bf16 rows, fp32 accum) ----------------
__device__ inline void acc_bf16(float4& acc, uint2 v, float w) {
  acc.x = fmaf(w, __uint_as_float(v.x << 16), acc.x);
  acc.y = fmaf(w, __uint_as_float(v.x & 0xffff0000u), acc.y);
  acc.z = fmaf(w, __uint_as_float(v.y << 16), acc.z);
  acc.w = fmaf(w, __uint_as_float(v.y & 0xffff0000u), acc.w);
}

__global__ __launch_bounds__(256) void gather_kernel(const uint2* __restrict__ xh,
                                                     const int2* __restrict__ edges,
                                                     const int* __restrict__ off,
                                                     const int* __restrict__ cnt,
                                                     float4* __restrict__ agg4, int N) {
  int d = blockIdx.x * 4 + (threadIdx.x >> 6);
  if (d >= N) return;
  int lane = threadIdx.x & 63;
  int start = off[d], n = cnt[d];
  float4 acc = make_float4(0.f, 0.f, 0.f, 0.f);
  int j = 0;
  for (; j + 3 < n; j += 4) {
    int2 e0 = edges[start + j];
    int2 e1 = edges[start + j + 1];
    int2 e2 = edges[start + j + 2];
    int2 e3 = edges[start + j + 3];
    uint2 v0 = xh[(size_t)e0.x * 64 + lane];
    uint2 v1 = xh[(size_t)e1.x * 64 + lane];
    uint2 v2 = xh[(size_t)e2.x * 64 + lane];
    uint2 v3 = xh[(size_t)e3.x * 64 + lane];
    acc_bf16(acc, v0, __int_as_float(e0.y));
    acc_bf16(acc, v1, __int_as_float(e1.y));
    acc_bf16(acc, v2, __int_as_float(e2.y));
    acc_bf16(acc, v3, __int_as_float(e3.y));
  }
  for (; j < n; j++) {
    int2 e0 = edges[start + j];
    uint2 v0 = xh[(size_t)e0.x * 64 + lane];
    acc_bf16(acc, v0, __int_as_float(e0.y));
  }
  agg4[(size_t)d * 64 + lane] = acc;
}

// ---------------- fp32 GEMM + fused BN partial stats ----------------
#define BM 64
#define BK 32
__global__ __launch_bounds__(256) void gemm_kernel(const float* __restrict__ agg,
                                                   const float* __restrict__ ham,
                                                   float* __restrict__ out,
                                                   float* __restrict__ bnsum, int N) {
  __shared__ float As[BK][68];
  __shared__ float Bs[BK][256];
  __shared__ float csum[256];
  __shared__ float csq[256];
  const int tid = threadIdx.x;
  const int tx = tid & 31;
  const int ty = tid >> 5;
  const int row0 = blockIdx.x * BM;
  const int r = tid & 63, h = tid >> 6;

  csum[tid] = 0.f; csq[tid] = 0.f;

  float acc[8][8];
  #pragma unroll
  for (int i = 0; i < 8; i++)
    #pragma unroll
    for (int j = 0; j < 8; j++) acc[i][j] = 0.f;

  const float4* agg4 = (const float4*)agg;
  const float4* ham4 = (const float4*)ham;
  const int grow = row0 + r;

  for (int k0 = 0; k0 < 256; k0 += BK) {
    #pragma unroll
    for (int ff = 0; ff < 2; ff++) {
      int f = h + ff * 4;
      float4 v = make_float4(0.f, 0.f, 0.f, 0.f);
      if (grow < N) v = agg4[(size_t)grow * 64 + (k0 >> 2) + f];
      As[f * 4 + 0][r] = v.x; As[f * 4 + 1][r] = v.y;
      As[f * 4 + 2][r] = v.z; As[f * 4 + 3][r] = v.w;
    }
    #pragma unroll
    for (int i = 0; i < 8; i++) {
      int idx = tid + i * 256;
      int kr = idx >> 6, c4 = idx & 63;
      float4 v = ham4[(size_t)(k0 + kr) * 64 + c4];
      *(float4*)&Bs[kr][c4 * 4] = v;
    }
    __syncthreads();

    #pragma unroll 4
    for (int k = 0; k < BK; k++) {
      float a[8], b[8];
      *(float4*)&a[0] = *(const float4*)&As[k][ty * 8];
      *(float4*)&a[4] = *(const float4*)&As[k][ty * 8 + 4];
      *(float4*)&b[0] = *(const float4*)&Bs[k][tx * 8];
      *(float4*)&b[4] = *(const float4*)&Bs[k][tx * 8 + 4];
      #pragma unroll
      for (int i = 0; i < 8; i++)
        #pragma unroll
        for (int j = 0; j < 8; j++) acc[i][j] = fmaf(a[i], b[j], acc[i][j]);
    }
    __syncthreads();
  }

  float4* out4 = (float4*)out;
  #pragma unroll
  for (int i = 0; i < 8; i++) {
    int gr = row0 + ty * 8 + i;
    if (gr < N) {
      out4[(size_t)gr * 64 + tx * 2]     = make_float4(acc[i][0], acc[i][1], acc[i][2], acc[i][3]);
      out4[(size_t)gr * 64 + tx * 2 + 1] = make_float4(acc[i][4], acc[i][5], acc[i][6], acc[i][7]);
    }
  }

  // fused BN partials (OOB rows contribute exact zeros)
  #pragma unroll
  for (int j = 0; j < 8; j++) {
    float s = 0.f, q = 0.f;
    #pragma unroll
    for (int i = 0; i < 8; i++) { s += acc[i][j]; q = fmaf(acc[i][j], acc[i][j], q); }
    atomicAdd(&csum[tx * 8 + j], s);
    atomicAdd(&csq[tx * 8 + j], q);
  }
  __syncthreads();
  atomicAdd(&bnsum[tid], csum[tid]);
  atomicAdd(&bnsum[256 + tid], csq[tid]);
}

__global__ void bnscale_kernel(const float* __restrict__ bnsum,
                               const float* __restrict__ gamma,
                               const float* __restrict__ beta,
                               float* __restrict__ bnsc, int N) {
  int c = threadIdx.x;
  float invN = 1.f / (float)N;
  float mean = bnsum[c] * invN;
  float var  = bnsum[256 + c] * invN - mean * mean;
  float sc = rsqrtf(var + 1e-5f) * gamma[c];
  bnsc[c] = sc;
  bnsc[256 + c] = beta[c] - mean * sc;
}

__global__ __launch_bounds__(256) void final_kernel(float* __restrict__ out,
                                                    const float* __restrict__ bnsc,
                                                    size_t total4) {
  size_t idx = (size_t)blockIdx.x * 256 + threadIdx.x;
  size_t stride = (size_t)gridDim.x * 256;
  float4* out4 = (float4*)out;
  for (size_t i = idx; i < total4; i += stride) {
    float4 v = out4[i];
    int c0 = (int)((i * 4) & 255);
    v.x = tanhf(fmaf(v.x, bnsc[c0 + 0], bnsc[256 + c0 + 0]));
    v.y = tanhf(fmaf(v.y, bnsc[c0 + 1], bnsc[256 + c0 + 1]));
    v.z = tanhf(fmaf(v.z, bnsc[c0 + 2], bnsc[256 + c0 + 2]));
    v.w = tanhf(fmaf(v.w, bnsc[c0 + 3], bnsc[256 + c0 + 3]));
    out4[i] = v;
  }
}

// ---------------- launch ----------------
extern "C" void kernel_launch(void* const* d_in, const int* in_sizes, int n_in,
                              void* d_out, int out_size, void* d_ws, size_t ws_size,
                              hipStream_t stream) {
  const float* x      = (const float*)d_in[0];
  const float* weight = (const float*)d_in[1];
  const float* gamma  = (const float*)d_in[2];
  const float* beta   = (const float*)d_in[3];
  const float* ew     = (const float*)d_in[4];
  const int*   esrc   = (const int*)d_in[5];
  const int*   edst   = (const int*)d_in[6];
  const int N = in_sizes[0] / 256;
  const int E = in_sizes[4];
  float* out = (float*)d_out;

  char* p = (char*)d_ws;
  auto alloc = [&](size_t bytes) {
    char* q = p;
    p += (bytes + 255) & ~(size_t)255;
    return q;
  };
  float* ham       = (float*)alloc(256 * 256 * 4);
  int*   binTot    = (int*)alloc(NB * 4);
  int*   binStart  = (int*)alloc((NB + 1) * 4);
  int*   binCursor = (int*)alloc(NB * 4);
  int*   cnt       = (int*)alloc((size_t)N * 4);
  int*   off       = (int*)alloc((size_t)N * 4);
  int2*  bb_sw     = (int2*)alloc((size_t)E * 8);
  int*   bb_d      = (int*)alloc((size_t)E * 4);
  int2*  edges     = (int2*)alloc((size_t)E * 8);
  uint2* xh        = (uint2*)alloc((size_t)N * 256 * 2);
  float* bnsum     = (float*)alloc(512 * 4);
  float* bnsc      = (float*)alloc(512 * 4);
  float* agg       = out;   // alias: gemm is in-place-safe per block

  hipMemsetAsync(binTot, 0, NB * 4, stream);
  hipMemsetAsync(bnsum, 0, 512 * 4, stream);

  const int gridE = (E + CHUNK - 1) / CHUNK;

  ham_kernel<<<256, 256, 0, stream>>>(weight, ham);
  cvt_kernel<<<2048, 256, 0, stream>>>((const float4*)x, xh, (size_t)N * 64);
  binhist_kernel<<<gridE, 256, 0, stream>>>(edst, binTot, E, N);
  binscan_kernel<<<1, 512, 0, stream>>>(binTot, binStart, binCursor, E);
  bin_scatter<<<gridE, 256, 0, stream>>>(esrc, edst, ew, binCursor, bb_sw, bb_d, E, N);
  bin_place<<<NB, 256, 0, stream>>>(bb_sw, bb_d, binStart, off, cnt, edges, N);
  gather_kernel<<<(N + 3) / 4, 256, 0, stream>>>(xh, edges, off, cnt, (float4*)agg, N);
  gemm_kernel<<<(N + BM - 1) / BM, 256, 0, stream>>>(agg, ham, out, bnsum, N);
  bnscale_kernel<<<1, 256, 0, stream>>>(bnsum, gamma, beta, bnsc, N);
  final_kernel<<<2048, 256, 0, stream>>>(out, bnsc, (size_t)N * 64);
}

// Round 4
// 695.888 us; speedup vs baseline: 1.7244x; 1.0072x over previous
//
#include <hip/hip_runtime.h>
#include <cmath>

#define NB 512        // dst-range bins
#define CHUNK 8192    // edges per block in binning kernels

typedef short short8 __attribute__((ext_vector_type(8)));
typedef float f32x4 __attribute__((ext_vector_type(4)));

// ---------------- octonion tables: indexed [c][r] ----------------
__constant__ int c_IDX[64] = {
  0,1,2,3,4,5,6,7,
  1,0,3,2,5,4,7,6,
  2,3,0,1,6,7,4,5,
  3,2,1,0,7,6,5,4,
  4,5,6,7,0,1,2,3,
  5,4,7,6,1,0,3,2,
  6,7,4,5,2,3,0,1,
  7,6,5,4,3,2,1,0};
__constant__ float c_SIGN[64] = {
  1,1,1,1,1,1,1,1,
  1,-1,1,-1,1,-1,-1,1,
  1,-1,-1,1,1,1,-1,-1,
  1,1,-1,-1,1,-1,1,-1,
  1,-1,-1,-1,-1,1,1,1,
  1,1,-1,1,-1,-1,-1,1,
  1,1,1,-1,-1,1,-1,-1,
  1,-1,1,1,-1,-1,1,-1};

__device__ inline unsigned bf16_rne(float f) {
  unsigned u = __float_as_uint(f);
  return (u + 0x7fffu + ((u >> 16) & 1u)) >> 16;
}
__device__ inline unsigned bfpack(float lo, float hi) {
  return bf16_rne(lo) | (bf16_rne(hi) << 16);
}

// hamT planes (transposed hamilton, bf16 hi+lo split): hamT[col*256 + k]
__global__ __launch_bounds__(256) void hamT_kernel(const float* __restrict__ weight,
                                                   unsigned short* __restrict__ hi,
                                                   unsigned short* __restrict__ lo) {
  int idx = blockIdx.x * 256 + threadIdx.x;   // 65536
  int col = idx >> 8, k = idx & 255;
  int r = k >> 5, i = k & 31, c = col >> 5, o = col & 31;
  float v = c_SIGN[c * 8 + r] * weight[i * 256 + c_IDX[c * 8 + r] * 32 + o];
  unsigned hb = bf16_rne(v);
  float hf = __uint_as_float(hb << 16);
  hi[idx] = (unsigned short)hb;
  lo[idx] = (unsigned short)bf16_rne(v - hf);
}

// ---------------- x -> packed bf16 (RNE) ----------------
__global__ __launch_bounds__(256) void cvt_kernel(const float4* __restrict__ x4,
                                                  uint2* __restrict__ xh, size_t n4) {
  size_t idx = (size_t)blockIdx.x * 256 + threadIdx.x;
  size_t stride = (size_t)gridDim.x * 256;
  for (size_t i = idx; i < n4; i += stride) {
    float4 v = x4[i];
    xh[i] = make_uint2(bfpack(v.x, v.y), bfpack(v.z, v.w));
  }
}

// ---------------- bin histogram (LDS-aggregated) ----------------
__global__ __launch_bounds__(256) void binhist_kernel(const int* __restrict__ dst,
                                                      int* __restrict__ binTot,
                                                      int E, int N) {
  __shared__ int h[NB];
  int tid = threadIdx.x;
  for (int i = tid; i < NB; i += 256) h[i] = 0;
  __syncthreads();
  int base = blockIdx.x * CHUNK;
  int end = base + CHUNK; if (end > E) end = E;
  for (int i = base + tid; i < end; i += 256)
    atomicAdd(&h[(int)((long long)dst[i] * NB / N)], 1);
  __syncthreads();
  for (int i = tid; i < NB; i += 256)
    if (h[i]) atomicAdd(&binTot[i], h[i]);
}

__global__ __launch_bounds__(512) void binscan_kernel(const int* __restrict__ binTot,
                                                      int* __restrict__ binStart,
                                                      int* __restrict__ binCursor, int E) {
  __shared__ int wsum[8], wbase[8];
  int tid = threadIdx.x, lane = tid & 63, wid = tid >> 6;
  int v = binTot[tid];
  int incl = v;
  #pragma unroll
  for (int d = 1; d < 64; d <<= 1) { int u = __shfl_up(incl, d); if (lane >= d) incl += u; }
  if (lane == 63) wsum[wid] = incl;
  __syncthreads();
  if (tid == 0) { int s = 0; for (int w = 0; w < 8; w++) { wbase[w] = s; s += wsum[w]; } }
  __syncthreads();
  int excl = wbase[wid] + incl - v;
  binStart[tid] = excl;
  binCursor[tid] = excl;
  if (tid == NB - 1) binStart[NB] = E;
}

// ---------------- pass 1: scatter edges into dst-range bins ----------------
// bb entry: (src | dloc<<24, w)  -- dloc = d - d0(bin), nd<=196<256, src<2^24
__global__ __launch_bounds__(256) void bin_scatter(const int* __restrict__ src,
                                                   const int* __restrict__ dst,
                                                   const float* __restrict__ w,
                                                   int* __restrict__ binCursor,
                                                   int2* __restrict__ bb, int E, int N) {
  __shared__ int hist[NB];
  __shared__ int lcur[NB];
  int tid = threadIdx.x;
  int base = blockIdx.x * CHUNK;
  int end = base + CHUNK; if (end > E) end = E;
  for (int i = tid; i < NB; i += 256) hist[i] = 0;
  __syncthreads();
  for (int i = base + tid; i < end; i += 256)
    atomicAdd(&hist[(int)((long long)dst[i] * NB / N)], 1);
  __syncthreads();
  for (int i = tid; i < NB; i += 256) {
    int h = hist[i];
    lcur[i] = h ? atomicAdd(&binCursor[i], h) : 0;
  }
  __syncthreads();
  for (int i = base + tid; i < end; i += 256) {
    int d = dst[i];
    int b = (int)((long long)d * NB / N);
    int d0 = (int)(((long long)b * N + NB - 1) / NB);
    int pos = atomicAdd(&lcur[b], 1);
    bb[pos] = make_int2(src[i] | ((d - d0) << 24), __float_as_int(w[i]));
  }
}

// ---------------- pass 2: per-bin local CSR + exact placement ----------------
__global__ __launch_bounds__(256) void bin_place(const int2* __restrict__ bb,
                                                 const int* __restrict__ binStart,
                                                 int* __restrict__ off,
                                                 int* __restrict__ cnt,
                                                 int2* __restrict__ edges, int N) {
  __shared__ int lcnt[208];
  __shared__ int loff[208];
  int b = blockIdx.x, tid = threadIdx.x;
  int d0 = (int)(((long long)b * N + NB - 1) / NB);
  int d1 = (int)(((long long)(b + 1) * N + NB - 1) / NB);
  if (d1 > N) d1 = N;
  int nd = d1 - d0;
  int e0 = binStart[b], e1 = binStart[b + 1];
  for (int i = tid; i < nd; i += 256) lcnt[i] = 0;
  __syncthreads();
  for (int i = e0 + tid; i < e1; i += 256)
    atomicAdd(&lcnt[((unsigned)bb[i].x) >> 24], 1);
  __syncthreads();
  if (tid == 0) {
    int s = e0;
    for (int i = 0; i < nd; i++) { loff[i] = s; s += lcnt[i]; }
  }
  __syncthreads();
  for (int i = tid; i < nd; i += 256) {
    off[d0 + i] = loff[i];
    cnt[d0 + i] = lcnt[i];
  }
  __syncthreads();
  for (int i = tid; i < nd; i += 256) lcnt[i] = loff[i];  // reuse as cursors
  __syncthreads();
  for (int i = e0 + tid; i < e1; i += 256) {
    int2 e = bb[i];
    int pos = atomicAdd(&lcnt[((unsigned)e.x) >> 24], 1);
    edges[pos] = make_int2(e.x & 0xFFFFFF, e.y);
  }
}

// ---------------- gather-aggregate (bf16 rows via uint4, fp32 accum) ----------
// one wave per dst row; 32 lanes cover the 512B row; halves process 2 edges/iter
__device__ inline void acc8(float (&a)[8], uint4 v, float w) {
  a[0] = fmaf(w, __uint_as_float(v.x << 16), a[0]);
  a[1] = fmaf(w, __uint_as_float(v.x & 0xffff0000u), a[1]);
  a[2] = fmaf(w, __uint_as_float(v.y << 16), a[2]);
  a[3] = fmaf(w, __uint_as_float(v.y & 0xffff0000u), a[3]);
  a[4] = fmaf(w, __uint_as_float(v.z << 16), a[4]);
  a[5] = fmaf(w, __uint_as_float(v.z & 0xffff0000u), a[5]);
  a[6] = fmaf(w, __uint_as_float(v.w << 16), a[6]);
  a[7] = fmaf(w, __uint_as_float(v.w & 0xffff0000u), a[7]);
}

__global__ __launch_bounds__(256) void gather_kernel(const uint4* __restrict__ x16,
                                                     const int2* __restrict__ edges,
                                                     const int* __restrict__ off,
                                                     const int* __restrict__ cnt,
                                                     uint4* __restrict__ agg16, int N) {
  int d = blockIdx.x * 4 + (threadIdx.x >> 6);
  if (d >= N) return;
  int lane = threadIdx.x & 63;
  int h = lane >> 5, c = lane & 31;
  int start = off[d], n = cnt[d];
  float a[8] = {0.f, 0.f, 0.f, 0.f, 0.f, 0.f, 0.f, 0.f};
  int m = (n - h + 1) >> 1;   // iterations for this half (edges h, h+2, ...)
  int t = 0;
  for (; t + 1 < m; t += 2) {
    int2 e0 = edges[start + 2 * t + h];
    int2 e1 = edges[start + 2 * t + 2 + h];
    uint4 v0 = x16[(size_t)e0.x * 32 + c];
    uint4 v1 = x16[(size_t)e1.x * 32 + c];
    acc8(a, v0, __int_as_float(e0.y));
    acc8(a, v1, __int_as_float(e1.y));
  }
  if (t < m) {
    int2 e0 = edges[start + 2 * t + h];
    uint4 v0 = x16[(size_t)e0.x * 32 + c];
    acc8(a, v0, __int_as_float(e0.y));
  }
  #pragma unroll
  for (int i = 0; i < 8; i++) a[i] += __shfl_xor(a[i], 32);
  if (h == 0)
    agg16[(size_t)d * 32 + c] = make_uint4(bfpack(a[0], a[1]), bfpack(a[2], a[3]),
                                           bfpack(a[4], a[5]), bfpack(a[6], a[7]));
}

// ---------------- MFMA GEMM: out = agg[Nx256](bf16) @ (hamT_hi+hamT_lo)^T -----
// 128x128 tile, A + B^T colblock fully LDS-resident (XOR-swizzled), 4 waves.
// phase 0: accumulate BN sum/sumsq only. phase 1: apply BN+tanh, write out.
__global__ __launch_bounds__(256) void mfma_gemm(const uint4* __restrict__ aggh,
                                                 const unsigned short* __restrict__ hamT_hi,
                                                 const unsigned short* __restrict__ hamT_lo,
                                                 float* __restrict__ bnsum,
                                                 const float* __restrict__ bnsc,
                                                 float* __restrict__ out,
                                                 int N, int phase) {
  __shared__ __align__(16) unsigned short Al[128 * 256];  // 64 KB
  __shared__ __align__(16) unsigned short Bl[128 * 256];  // 64 KB
  __shared__ float csum[128], csq[128];
  const int tid = threadIdx.x;
  const int row0 = blockIdx.x * 128;
  const int col0 = blockIdx.y * 128;
  const int lane = tid & 63, wv = tid >> 6;
  const int wm = wv >> 1, wn = wv & 1;

  if (tid < 128) { csum[tid] = 0.f; csq[tid] = 0.f; }

  // stage A: 128 rows x 256 k (one-shot), zero-fill OOB rows
  #pragma unroll
  for (int it = 0; it < 16; it++) {
    int cidx = it * 256 + tid;
    int row = cidx >> 5, c16 = cidx & 31;
    int rg = row0 + row;
    uint4 v = make_uint4(0u, 0u, 0u, 0u);
    if (rg < N) v = aggh[(size_t)rg * 32 + c16];
    *(uint4*)((char*)Al + row * 512 + ((c16 * 16) ^ ((row & 7) << 4))) = v;
  }

  f32x4 acc[4][4];
  #pragma unroll
  for (int m = 0; m < 4; m++)
    #pragma unroll
    for (int n = 0; n < 4; n++) acc[m][n] = (f32x4)0.f;

  const uint4* hamp[2] = {(const uint4*)hamT_hi, (const uint4*)hamT_lo};
  for (int pl = 0; pl < 2; pl++) {
    __syncthreads();   // pl=0: A+csum ready; pl=1: Bl(hi) reads done
    const uint4* srcp = hamp[pl];
    #pragma unroll
    for (int it = 0; it < 16; it++) {
      int cidx = it * 256 + tid;
      int colr = cidx >> 5, c16 = cidx & 31;
      uint4 v = srcp[(size_t)(col0 + colr) * 32 + c16];
      *(uint4*)((char*)Bl + colr * 512 + ((c16 * 16) ^ ((colr & 7) << 4))) = v;
    }
    __syncthreads();
    #pragma unroll
    for (int kk = 0; kk < 8; kk++) {
      short8 af[4], bfr[4];
      int kbyte = (lane >> 4) * 16 + kk * 64;
      #pragma unroll
      for (int m = 0; m < 4; m++) {
        int row = wm * 64 + m * 16 + (lane & 15);
        af[m] = *(const short8*)((const char*)Al + row * 512 + (kbyte ^ ((row & 7) << 4)));
        int col = wn * 64 + m * 16 + (lane & 15);
        bfr[m] = *(const short8*)((const char*)Bl + col * 512 + (kbyte ^ ((col & 7) << 4)));
      }
      #pragma unroll
      for (int m = 0; m < 4; m++)
        #pragma unroll
        for (int n = 0; n < 4; n++)
          acc[m][n] = __builtin_amdgcn_mfma_f32_16x16x32_bf16(af[m], bfr[n], acc[m][n], 0, 0, 0);
    }
  }

  if (phase == 0) {
    #pragma unroll
    for (int n = 0; n < 4; n++) {
      float s = 0.f, q = 0.f;
      #pragma unroll
      for (int m = 0; m < 4; m++)
        #pragma unroll
        for (int r = 0; r < 4; r++) { float v = acc[m][n][r]; s += v; q = fmaf(v, v, q); }
      s += __shfl_xor(s, 16); s += __shfl_xor(s, 32);
      q += __shfl_xor(q, 16); q += __shfl_xor(q, 32);
      if (lane < 16) {
        atomicAdd(&csum[wn * 64 + n * 16 + lane], s);
        atomicAdd(&csq [wn * 64 + n * 16 + lane], q);
      }
    }
    __syncthreads();
    if (tid < 128) {
      atomicAdd(&bnsum[col0 + tid], csum[tid]);
      atomicAdd(&bnsum[256 + col0 + tid], csq[tid]);
    }
  } else {
    #pragma unroll
    for (int n = 0; n < 4; n++) {
      int colg = col0 + wn * 64 + n * 16 + (lane & 15);
      float sc = bnsc[colg], bo = bnsc[256 + colg];
      #pragma unroll
      for (int m = 0; m < 4; m++) {
        int rgb = row0 + wm * 64 + m * 16 + (lane >> 4) * 4;
        #pragma unroll
        for (int r = 0; r < 4; r++) {
          int rg = rgb + r;
          if (rg < N) out[(size_t)rg * 256 + colg] = tanhf(fmaf(acc[m][n][r], sc, bo));
        }
      }
    }
  }
}

__global__ void bnscale_kernel(const float* __restrict__ bnsum,
                               const float* __restrict__ gamma,
                               const float* __restrict__ beta,
                               float* __restrict__ bnsc, int N) {
  int c = threadIdx.x;
  float invN = 1.f / (float)N;
  float mean = bnsum[c] * invN;
  float var  = bnsum[256 + c] * invN - mean * mean;
  float sc = rsqrtf(var + 1e-5f) * gamma[c];
  bnsc[c] = sc;
  bnsc[256 + c] = beta[c] - mean * sc;
}

// ---------------- launch ----------------
extern "C" void kernel_launch(void* const* d_in, const int* in_sizes, int n_in,
                              void* d_out, int out_size, void* d_ws, size_t ws_size,
                              hipStream_t stream) {
  const float* x      = (const float*)d_in[0];
  const float* weight = (const float*)d_in[1];
  const float* gamma  = (const float*)d_in[2];
  const float* beta   = (const float*)d_in[3];
  const float* ew     = (const float*)d_in[4];
  const int*   esrc   = (const int*)d_in[5];
  const int*   edst   = (const int*)d_in[6];
  const int N = in_sizes[0] / 256;
  const int E = in_sizes[4];
  float* out = (float*)d_out;

  char* p = (char*)d_ws;
  auto alloc = [&](size_t bytes) {
    char* q = p;
    p += (bytes + 255) & ~(size_t)255;
    return q;
  };
  unsigned short* hamT_hi = (unsigned short*)alloc(65536 * 2);
  unsigned short* hamT_lo = (unsigned short*)alloc(65536 * 2);
  int*   binTot    = (int*)alloc(NB * 4);
  int*   binStart  = (int*)alloc((NB + 1) * 4);
  int*   binCursor = (int*)alloc(NB * 4);
  int*   cnt       = (int*)alloc((size_t)N * 4);
  int*   off       = (int*)alloc((size_t)N * 4);
  int2*  bb        = (int2*)alloc((size_t)E * 8);
  int2*  edges     = (int2*)alloc((size_t)E * 8);
  uint2* xh        = (uint2*)alloc((size_t)N * 256 * 2);
  uint4* aggh      = (uint4*)alloc((size_t)N * 256 * 2);
  float* bnsum     = (float*)alloc(512 * 4);
  float* bnsc      = (float*)alloc(512 * 4);

  hipMemsetAsync(binTot, 0, NB * 4, stream);
  hipMemsetAsync(bnsum, 0, 512 * 4, stream);

  const int gridE = (E + CHUNK - 1) / CHUNK;
  const int rowBlocks = (N + 127) / 128;

  hamT_kernel<<<256, 256, 0, stream>>>(weight, hamT_hi, hamT_lo);
  cvt_kernel<<<2048, 256, 0, stream>>>((const float4*)x, xh, (size_t)N * 64);
  binhist_kernel<<<gridE, 256, 0, stream>>>(edst, binTot, E, N);
  binscan_kernel<<<1, 512, 0, stream>>>(binTot, binStart, binCursor, E);
  bin_scatter<<<gridE, 256, 0, stream>>>(esrc, edst, ew, binCursor, bb, E, N);
  bin_place<<<NB, 256, 0, stream>>>(bb, binStart, off, cnt, edges, N);
  gather_kernel<<<(N + 3) / 4, 256, 0, stream>>>((const uint4*)xh, edges, off, cnt, aggh, N);
  mfma_gemm<<<dim3(rowBlocks, 2), 256, 0, stream>>>(aggh, hamT_hi, hamT_lo, bnsum, bnsc, out, N, 0);
  bnscale_kernel<<<1, 256, 0, stream>>>(bnsum, gamma, beta, bnsc, N);
  mfma_gemm<<<dim3(rowBlocks, 2), 256, 0, stream>>>(aggh, hamT_hi, hamT_lo, bnsum, bnsc, out, N, 1);
}

// Round 5
// 521.026 us; speedup vs baseline: 2.3032x; 1.3356x over previous
//
#include <hip/hip_runtime.h>
#include <cmath>

#define NB 512        // dst-range bins
#define CHUNK 8192    // edges per block in binning kernels

typedef short short8 __attribute__((ext_vector_type(8)));
typedef float f32x4 __attribute__((ext_vector_type(4)));

// ---------------- octonion tables: indexed [c][r] ----------------
__constant__ int c_IDX[64] = {
  0,1,2,3,4,5,6,7,
  1,0,3,2,5,4,7,6,
  2,3,0,1,6,7,4,5,
  3,2,1,0,7,6,5,4,
  4,5,6,7,0,1,2,3,
  5,4,7,6,1,0,3,2,
  6,7,4,5,2,3,0,1,
  7,6,5,4,3,2,1,0};
__constant__ float c_SIGN[64] = {
  1,1,1,1,1,1,1,1,
  1,-1,1,-1,1,-1,-1,1,
  1,-1,-1,1,1,1,-1,-1,
  1,1,-1,-1,1,-1,1,-1,
  1,-1,-1,-1,-1,1,1,1,
  1,1,-1,1,-1,-1,-1,1,
  1,1,1,-1,-1,1,-1,-1,
  1,-1,1,1,-1,-1,1,-1};

__device__ inline unsigned bf16_rne(float f) {
  unsigned u = __float_as_uint(f);
  return (u + 0x7fffu + ((u >> 16) & 1u)) >> 16;
}
__device__ inline unsigned bfpack(float lo, float hi) {
  return bf16_rne(lo) | (bf16_rne(hi) << 16);
}

// hamT planes (transposed hamilton, bf16 hi+lo split): hamT[col*256 + k]
__global__ __launch_bounds__(256) void hamT_kernel(const float* __restrict__ weight,
                                                   unsigned short* __restrict__ hi,
                                                   unsigned short* __restrict__ lo) {
  int idx = blockIdx.x * 256 + threadIdx.x;   // 65536
  int col = idx >> 8, k = idx & 255;
  int r = k >> 5, i = k & 31, c = col >> 5, o = col & 31;
  float v = c_SIGN[c * 8 + r] * weight[i * 256 + c_IDX[c * 8 + r] * 32 + o];
  unsigned hb = bf16_rne(v);
  float hf = __uint_as_float(hb << 16);
  hi[idx] = (unsigned short)hb;
  lo[idx] = (unsigned short)bf16_rne(v - hf);
}

// ---------------- x -> packed bf16 (RNE) ----------------
__global__ __launch_bounds__(256) void cvt_kernel(const float4* __restrict__ x4,
                                                  uint2* __restrict__ xh, size_t n4) {
  size_t idx = (size_t)blockIdx.x * 256 + threadIdx.x;
  size_t stride = (size_t)gridDim.x * 256;
  for (size_t i = idx; i < n4; i += stride) {
    float4 v = x4[i];
    xh[i] = make_uint2(bfpack(v.x, v.y), bfpack(v.z, v.w));
  }
}

// ---------------- bin histogram (LDS-aggregated) ----------------
__global__ __launch_bounds__(256) void binhist_kernel(const int* __restrict__ dst,
                                                      int* __restrict__ binTot,
                                                      int E, int N) {
  __shared__ int h[NB];
  int tid = threadIdx.x;
  for (int i = tid; i < NB; i += 256) h[i] = 0;
  __syncthreads();
  int base = blockIdx.x * CHUNK;
  int end = base + CHUNK; if (end > E) end = E;
  for (int i = base + tid; i < end; i += 256)
    atomicAdd(&h[(int)((long long)dst[i] * NB / N)], 1);
  __syncthreads();
  for (int i = tid; i < NB; i += 256)
    if (h[i]) atomicAdd(&binTot[i], h[i]);
}

__global__ __launch_bounds__(512) void binscan_kernel(const int* __restrict__ binTot,
                                                      int* __restrict__ binStart,
                                                      int* __restrict__ binCursor, int E) {
  __shared__ int wsum[8], wbase[8];
  int tid = threadIdx.x, lane = tid & 63, wid = tid >> 6;
  int v = binTot[tid];
  int incl = v;
  #pragma unroll
  for (int d = 1; d < 64; d <<= 1) { int u = __shfl_up(incl, d); if (lane >= d) incl += u; }
  if (lane == 63) wsum[wid] = incl;
  __syncthreads();
  if (tid == 0) { int s = 0; for (int w = 0; w < 8; w++) { wbase[w] = s; s += wsum[w]; } }
  __syncthreads();
  int excl = wbase[wid] + incl - v;
  binStart[tid] = excl;
  binCursor[tid] = excl;
  if (tid == NB - 1) binStart[NB] = E;
}

// ---------------- pass 1: scatter edges into dst-range bins ----------------
// bb entry: (src | dloc<<24, w)  -- dloc = d - d0(bin), nd<=196<256, src<2^24
__global__ __launch_bounds__(256) void bin_scatter(const int* __restrict__ src,
                                                   const int* __restrict__ dst,
                                                   const float* __restrict__ w,
                                                   int* __restrict__ binCursor,
                                                   int2* __restrict__ bb, int E, int N) {
  __shared__ int hist[NB];
  __shared__ int lcur[NB];
  int tid = threadIdx.x;
  int base = blockIdx.x * CHUNK;
  int end = base + CHUNK; if (end > E) end = E;
  for (int i = tid; i < NB; i += 256) hist[i] = 0;
  __syncthreads();
  for (int i = base + tid; i < end; i += 256)
    atomicAdd(&hist[(int)((long long)dst[i] * NB / N)], 1);
  __syncthreads();
  for (int i = tid; i < NB; i += 256) {
    int h = hist[i];
    lcur[i] = h ? atomicAdd(&binCursor[i], h) : 0;
  }
  __syncthreads();
  for (int i = base + tid; i < end; i += 256) {
    int d = dst[i];
    int b = (int)((long long)d * NB / N);
    int d0 = (int)(((long long)b * N + NB - 1) / NB);
    int pos = atomicAdd(&lcur[b], 1);
    bb[pos] = make_int2(src[i] | ((d - d0) << 24), __float_as_int(w[i]));
  }
}

// ---------------- pass 2: per-bin local CSR + exact placement ----------------
__global__ __launch_bounds__(256) void bin_place(const int2* __restrict__ bb,
                                                 const int* __restrict__ binStart,
                                                 int* __restrict__ off,
                                                 int* __restrict__ cnt,
                                                 int2* __restrict__ edges, int N) {
  __shared__ int lcnt[208];
  __shared__ int loff[208];
  int b = blockIdx.x, tid = threadIdx.x;
  int d0 = (int)(((long long)b * N + NB - 1) / NB);
  int d1 = (int)(((long long)(b + 1) * N + NB - 1) / NB);
  if (d1 > N) d1 = N;
  int nd = d1 - d0;
  int e0 = binStart[b], e1 = binStart[b + 1];
  for (int i = tid; i < nd; i += 256) lcnt[i] = 0;
  __syncthreads();
  for (int i = e0 + tid; i < e1; i += 256)
    atomicAdd(&lcnt[((unsigned)bb[i].x) >> 24], 1);
  __syncthreads();
  if (tid == 0) {
    int s = e0;
    for (int i = 0; i < nd; i++) { loff[i] = s; s += lcnt[i]; }
  }
  __syncthreads();
  for (int i = tid; i < nd; i += 256) {
    off[d0 + i] = loff[i];
    cnt[d0 + i] = lcnt[i];
  }
  __syncthreads();
  for (int i = tid; i < nd; i += 256) lcnt[i] = loff[i];  // reuse as cursors
  __syncthreads();
  for (int i = e0 + tid; i < e1; i += 256) {
    int2 e = bb[i];
    int pos = atomicAdd(&lcnt[((unsigned)e.x) >> 24], 1);
    edges[pos] = make_int2(e.x & 0xFFFFFF, e.y);
  }
}

// ---------------- gather-aggregate (bf16 rows via uint4, fp32 accum) ----------
__device__ inline void acc8(float (&a)[8], uint4 v, float w) {
  a[0] = fmaf(w, __uint_as_float(v.x << 16), a[0]);
  a[1] = fmaf(w, __uint_as_float(v.x & 0xffff0000u), a[1]);
  a[2] = fmaf(w, __uint_as_float(v.y << 16), a[2]);
  a[3] = fmaf(w, __uint_as_float(v.y & 0xffff0000u), a[3]);
  a[4] = fmaf(w, __uint_as_float(v.z << 16), a[4]);
  a[5] = fmaf(w, __uint_as_float(v.z & 0xffff0000u), a[5]);
  a[6] = fmaf(w, __uint_as_float(v.w << 16), a[6]);
  a[7] = fmaf(w, __uint_as_float(v.w & 0xffff0000u), a[7]);
}

__global__ __launch_bounds__(256) void gather_kernel(const uint4* __restrict__ x16,
                                                     const int2* __restrict__ edges,
                                                     const int* __restrict__ off,
                                                     const int* __restrict__ cnt,
                                                     uint4* __restrict__ agg16, int N) {
  int d = blockIdx.x * 4 + (threadIdx.x >> 6);
  if (d >= N) return;
  int lane = threadIdx.x & 63;
  int h = lane >> 5, c = lane & 31;
  int start = off[d], n = cnt[d];
  float a[8] = {0.f, 0.f, 0.f, 0.f, 0.f, 0.f, 0.f, 0.f};
  int m = (n - h + 1) >> 1;   // iterations for this half (edges h, h+2, ...)
  int t = 0;
  for (; t + 1 < m; t += 2) {
    int2 e0 = edges[start + 2 * t + h];
    int2 e1 = edges[start + 2 * t + 2 + h];
    uint4 v0 = x16[(size_t)e0.x * 32 + c];
    uint4 v1 = x16[(size_t)e1.x * 32 + c];
    acc8(a, v0, __int_as_float(e0.y));
    acc8(a, v1, __int_as_float(e1.y));
  }
  if (t < m) {
    int2 e0 = edges[start + 2 * t + h];
    uint4 v0 = x16[(size_t)e0.x * 32 + c];
    acc8(a, v0, __int_as_float(e0.y));
  }
  #pragma unroll
  for (int i = 0; i < 8; i++) a[i] += __shfl_xor(a[i], 32);
  if (h == 0)
    agg16[(size_t)d * 32 + c] = make_uint4(bfpack(a[0], a[1]), bfpack(a[2], a[3]),
                                           bfpack(a[4], a[5]), bfpack(a[6], a[7]));
}

// ---------------- MFMA GEMM: out(fp32) = agg(bf16) @ (hamT_hi+hamT_lo)^T ------
// 128x256 (full-width) tile; 8 waves (2m x 4n); A in LDS (swizzled);
// B fragments straight from global (L2-hot, 256 KB); BN sum/sumsq fused.
__global__ __launch_bounds__(512) void mfma_gemm(const uint4* __restrict__ aggh,
                                                 const unsigned short* __restrict__ hamT_hi,
                                                 const unsigned short* __restrict__ hamT_lo,
                                                 float* __restrict__ bnsum,
                                                 float* __restrict__ out, int N) {
  __shared__ __align__(16) unsigned short Al[128 * 256];  // 64 KB
  __shared__ float csum[256], csq[256];
  const int tid = threadIdx.x;
  const int row0 = blockIdx.x * 128;
  const int lane = tid & 63, wv = tid >> 6;
  const int wm = wv >> 2, wn = wv & 3;   // wave tile: 64 rows x 64 cols

  if (tid < 256) { csum[tid] = 0.f; csq[tid] = 0.f; }

  // stage A: 128 rows x 256 k (one-shot), zero-fill OOB rows
  #pragma unroll
  for (int it = 0; it < 8; it++) {
    int cidx = it * 512 + tid;
    int row = cidx >> 5, c16 = cidx & 31;
    int rg = row0 + row;
    uint4 v = make_uint4(0u, 0u, 0u, 0u);
    if (rg < N) v = aggh[(size_t)rg * 32 + c16];
    *(uint4*)((char*)Al + row * 512 + ((c16 * 16) ^ ((row & 7) << 4))) = v;
  }
  __syncthreads();

  f32x4 acc[4][4];
  #pragma unroll
  for (int m = 0; m < 4; m++)
    #pragma unroll
    for (int n = 0; n < 4; n++) acc[m][n] = (f32x4)0.f;

  const char* bh = (const char*)hamT_hi;
  const char* bl = (const char*)hamT_lo;
  #pragma unroll
  for (int kk = 0; kk < 8; kk++) {
    const int kbyte = (lane >> 4) * 16 + kk * 64;
    short8 af[4];
    #pragma unroll
    for (int m = 0; m < 4; m++) {
      int row = wm * 64 + m * 16 + (lane & 15);
      af[m] = *(const short8*)((const char*)Al + row * 512 + (kbyte ^ ((row & 7) << 4)));
    }
    #pragma unroll
    for (int n = 0; n < 4; n++) {
      int colg = wn * 64 + n * 16 + (lane & 15);
      size_t boff = (size_t)colg * 512 + kbyte;
      short8 bhv = *(const short8*)(bh + boff);
      short8 blv = *(const short8*)(bl + boff);
      #pragma unroll
      for (int m = 0; m < 4; m++)
        acc[m][n] = __builtin_amdgcn_mfma_f32_16x16x32_bf16(af[m], bhv, acc[m][n], 0, 0, 0);
      #pragma unroll
      for (int m = 0; m < 4; m++)
        acc[m][n] = __builtin_amdgcn_mfma_f32_16x16x32_bf16(af[m], blv, acc[m][n], 0, 0, 0);
    }
  }

  // epilogue: write fp32 out + fused BN partials (OOB rows are exact zeros)
  #pragma unroll
  for (int n = 0; n < 4; n++) {
    int colg = wn * 64 + n * 16 + (lane & 15);
    float s = 0.f, q = 0.f;
    #pragma unroll
    for (int m = 0; m < 4; m++) {
      int rgb = row0 + wm * 64 + m * 16 + (lane >> 4) * 4;
      #pragma unroll
      for (int r = 0; r < 4; r++) {
        float v = acc[m][n][r];
        s += v; q = fmaf(v, v, q);
        int rg = rgb + r;
        if (rg < N) out[(size_t)rg * 256 + colg] = v;
      }
    }
    s += __shfl_xor(s, 16); s += __shfl_xor(s, 32);
    q += __shfl_xor(q, 16); q += __shfl_xor(q, 32);
    if (lane < 16) {
      atomicAdd(&csum[wn * 64 + n * 16 + lane], s);
      atomicAdd(&csq [wn * 64 + n * 16 + lane], q);
    }
  }
  __syncthreads();
  if (tid < 256) {
    atomicAdd(&bnsum[tid], csum[tid]);
    atomicAdd(&bnsum[256 + tid], csq[tid]);
  }
}

__global__ void bnscale_kernel(const float* __restrict__ bnsum,
                               const float* __restrict__ gamma,
                               const float* __restrict__ beta,
                               float* __restrict__ bnsc, int N) {
  int c = threadIdx.x;
  float invN = 1.f / (float)N;
  float mean = bnsum[c] * invN;
  float var  = bnsum[256 + c] * invN - mean * mean;
  float sc = rsqrtf(var + 1e-5f) * gamma[c];
  bnsc[c] = sc;
  bnsc[256 + c] = beta[c] - mean * sc;
}

__global__ __launch_bounds__(256) void final_kernel(float* __restrict__ out,
                                                    const float* __restrict__ bnsc,
                                                    size_t total4) {
  size_t idx = (size_t)blockIdx.x * 256 + threadIdx.x;
  size_t stride = (size_t)gridDim.x * 256;
  float4* out4 = (float4*)out;
  for (size_t i = idx; i < total4; i += stride) {
    float4 v = out4[i];
    int c0 = (int)((i * 4) & 255);
    v.x = tanhf(fmaf(v.x, bnsc[c0 + 0], bnsc[256 + c0 + 0]));
    v.y = tanhf(fmaf(v.y, bnsc[c0 + 1], bnsc[256 + c0 + 1]));
    v.z = tanhf(fmaf(v.z, bnsc[c0 + 2], bnsc[256 + c0 + 2]));
    v.w = tanhf(fmaf(v.w, bnsc[c0 + 3], bnsc[256 + c0 + 3]));
    out4[i] = v;
  }
}

// ---------------- launch ----------------
extern "C" void kernel_launch(void* const* d_in, const int* in_sizes, int n_in,
                              void* d_out, int out_size, void* d_ws, size_t ws_size,
                              hipStream_t stream) {
  const float* x      = (const float*)d_in[0];
  const float* weight = (const float*)d_in[1];
  const float* gamma  = (const float*)d_in[2];
  const float* beta   = (const float*)d_in[3];
  const float* ew     = (const float*)d_in[4];
  const int*   esrc   = (const int*)d_in[5];
  const int*   edst   = (const int*)d_in[6];
  const int N = in_sizes[0] / 256;
  const int E = in_sizes[4];
  float* out = (float*)d_out;

  char* p = (char*)d_ws;
  auto alloc = [&](size_t bytes) {
    char* q = p;
    p += (bytes + 255) & ~(size_t)255;
    return q;
  };
  unsigned short* hamT_hi = (unsigned short*)alloc(65536 * 2);
  unsigned short* hamT_lo = (unsigned short*)alloc(65536 * 2);
  int*   binTot    = (int*)alloc(NB * 4);
  int*   binStart  = (int*)alloc((NB + 1) * 4);
  int*   binCursor = (int*)alloc(NB * 4);
  int*   cnt       = (int*)alloc((size_t)N * 4);
  int*   off       = (int*)alloc((size_t)N * 4);
  int2*  bb        = (int2*)alloc((size_t)E * 8);
  int2*  edges     = (int2*)alloc((size_t)E * 8);
  uint2* xh        = (uint2*)alloc((size_t)N * 256 * 2);
  uint4* aggh      = (uint4*)alloc((size_t)N * 256 * 2);
  float* bnsum     = (float*)alloc(512 * 4);
  float* bnsc      = (float*)alloc(512 * 4);

  hipMemsetAsync(binTot, 0, NB * 4, stream);
  hipMemsetAsync(bnsum, 0, 512 * 4, stream);

  const int gridE = (E + CHUNK - 1) / CHUNK;
  const int rowBlocks = (N + 127) / 128;

  hamT_kernel<<<256, 256, 0, stream>>>(weight, hamT_hi, hamT_lo);
  cvt_kernel<<<2048, 256, 0, stream>>>((const float4*)x, xh, (size_t)N * 64);
  binhist_kernel<<<gridE, 256, 0, stream>>>(edst, binTot, E, N);
  binscan_kernel<<<1, 512, 0, stream>>>(binTot, binStart, binCursor, E);
  bin_scatter<<<gridE, 256, 0, stream>>>(esrc, edst, ew, binCursor, bb, E, N);
  bin_place<<<NB, 256, 0, stream>>>(bb, binStart, off, cnt, edges, N);
  gather_kernel<<<(N + 3) / 4, 256, 0, stream>>>((const uint4*)xh, edges, off, cnt, aggh, N);
  mfma_gemm<<<rowBlocks, 512, 0, stream>>>(aggh, hamT_hi, hamT_lo, bnsum, out, N);
  bnscale_kernel<<<1, 256, 0, stream>>>(bnsum, gamma, beta, bnsc, N);
  final_kernel<<<2048, 256, 0, stream>>>(out, bnsc, (size_t)N * 64);
}

// Round 6
// 501.652 us; speedup vs baseline: 2.3921x; 1.0386x over previous
//
#include <hip/hip_runtime.h>
#include <cmath>

#define NB 512        // dst-range bins
#define CHUNK 8192    // edges per block in binning kernels

typedef short short8 __attribute__((ext_vector_type(8)));
typedef float f32x4 __attribute__((ext_vector_type(4)));

// ---------------- octonion tables: indexed [c][r] ----------------
__constant__ int c_IDX[64] = {
  0,1,2,3,4,5,6,7,
  1,0,3,2,5,4,7,6,
  2,3,0,1,6,7,4,5,
  3,2,1,0,7,6,5,4,
  4,5,6,7,0,1,2,3,
  5,4,7,6,1,0,3,2,
  6,7,4,5,2,3,0,1,
  7,6,5,4,3,2,1,0};
__constant__ float c_SIGN[64] = {
  1,1,1,1,1,1,1,1,
  1,-1,1,-1,1,-1,-1,1,
  1,-1,-1,1,1,1,-1,-1,
  1,1,-1,-1,1,-1,1,-1,
  1,-1,-1,-1,-1,1,1,1,
  1,1,-1,1,-1,-1,-1,1,
  1,1,1,-1,-1,1,-1,-1,
  1,-1,1,1,-1,-1,1,-1};

__device__ inline unsigned bf16_rne(float f) {
  unsigned u = __float_as_uint(f);
  return (u + 0x7fffu + ((u >> 16) & 1u)) >> 16;
}
__device__ inline unsigned bfpack(float lo, float hi) {
  return bf16_rne(lo) | (bf16_rne(hi) << 16);
}

// hamT planes (transposed hamilton, bf16 hi+lo split): hamT[col*256 + k]
__global__ __launch_bounds__(256) void hamT_kernel(const float* __restrict__ weight,
                                                   unsigned short* __restrict__ hi,
                                                   unsigned short* __restrict__ lo) {
  int idx = blockIdx.x * 256 + threadIdx.x;   // 65536
  int col = idx >> 8, k = idx & 255;
  int r = k >> 5, i = k & 31, c = col >> 5, o = col & 31;
  float v = c_SIGN[c * 8 + r] * weight[i * 256 + c_IDX[c * 8 + r] * 32 + o];
  unsigned hb = bf16_rne(v);
  float hf = __uint_as_float(hb << 16);
  hi[idx] = (unsigned short)hb;
  lo[idx] = (unsigned short)bf16_rne(v - hf);
}

// ---------------- x -> packed bf16 (RNE) ----------------
__global__ __launch_bounds__(256) void cvt_kernel(const float4* __restrict__ x4,
                                                  uint2* __restrict__ xh, size_t n4) {
  size_t idx = (size_t)blockIdx.x * 256 + threadIdx.x;
  size_t stride = (size_t)gridDim.x * 256;
  for (size_t i = idx; i < n4; i += stride) {
    float4 v = x4[i];
    xh[i] = make_uint2(bfpack(v.x, v.y), bfpack(v.z, v.w));
  }
}

// ---------------- bin histogram (LDS-aggregated) ----------------
__global__ __launch_bounds__(256) void binhist_kernel(const int* __restrict__ dst,
                                                      int* __restrict__ binTot,
                                                      int E, int N) {
  __shared__ int h[NB];
  int tid = threadIdx.x;
  for (int i = tid; i < NB; i += 256) h[i] = 0;
  __syncthreads();
  int base = blockIdx.x * CHUNK;
  int end = base + CHUNK; if (end > E) end = E;
  for (int i = base + tid; i < end; i += 256)
    atomicAdd(&h[(int)((long long)dst[i] * NB / N)], 1);
  __syncthreads();
  for (int i = tid; i < NB; i += 256)
    if (h[i]) atomicAdd(&binTot[i], h[i]);
}

__global__ __launch_bounds__(512) void binscan_kernel(const int* __restrict__ binTot,
                                                      int* __restrict__ binStart,
                                                      int* __restrict__ binCursor, int E) {
  __shared__ int wsum[8], wbase[8];
  int tid = threadIdx.x, lane = tid & 63, wid = tid >> 6;
  int v = binTot[tid];
  int incl = v;
  #pragma unroll
  for (int d = 1; d < 64; d <<= 1) { int u = __shfl_up(incl, d); if (lane >= d) incl += u; }
  if (lane == 63) wsum[wid] = incl;
  __syncthreads();
  if (tid == 0) { int s = 0; for (int w = 0; w < 8; w++) { wbase[w] = s; s += wsum[w]; } }
  __syncthreads();
  int excl = wbase[wid] + incl - v;
  binStart[tid] = excl;
  binCursor[tid] = excl;
  if (tid == NB - 1) binStart[NB] = E;
}

// ---------------- pass 1: scatter edges into dst-range bins ----------------
// bb entry: (src | dloc<<24, w)  -- dloc = d - d0(bin), nd<=196<256, src<2^24
__global__ __launch_bounds__(256) void bin_scatter(const int* __restrict__ src,
                                                   const int* __restrict__ dst,
                                                   const float* __restrict__ w,
                                                   int* __restrict__ binCursor,
                                                   int2* __restrict__ bb, int E, int N) {
  __shared__ int hist[NB];
  __shared__ int lcur[NB];
  int tid = threadIdx.x;
  int base = blockIdx.x * CHUNK;
  int end = base + CHUNK; if (end > E) end = E;
  for (int i = tid; i < NB; i += 256) hist[i] = 0;
  __syncthreads();
  for (int i = base + tid; i < end; i += 256)
    atomicAdd(&hist[(int)((long long)dst[i] * NB / N)], 1);
  __syncthreads();
  for (int i = tid; i < NB; i += 256) {
    int h = hist[i];
    lcur[i] = h ? atomicAdd(&binCursor[i], h) : 0;
  }
  __syncthreads();
  for (int i = base + tid; i < end; i += 256) {
    int d = dst[i];
    int b = (int)((long long)d * NB / N);
    int d0 = (int)(((long long)b * N + NB - 1) / NB);
    int pos = atomicAdd(&lcur[b], 1);
    bb[pos] = make_int2(src[i] | ((d - d0) << 24), __float_as_int(w[i]));
  }
}

// ---------------- pass 2: per-bin local CSR + exact placement ----------------
__global__ __launch_bounds__(256) void bin_place(const int2* __restrict__ bb,
                                                 const int* __restrict__ binStart,
                                                 int* __restrict__ off,
                                                 int* __restrict__ cnt,
                                                 int2* __restrict__ edges, int N) {
  __shared__ int lcnt[208];
  __shared__ int loff[208];
  int b = blockIdx.x, tid = threadIdx.x;
  int d0 = (int)(((long long)b * N + NB - 1) / NB);
  int d1 = (int)(((long long)(b + 1) * N + NB - 1) / NB);
  if (d1 > N) d1 = N;
  int nd = d1 - d0;
  int e0 = binStart[b], e1 = binStart[b + 1];
  for (int i = tid; i < nd; i += 256) lcnt[i] = 0;
  __syncthreads();
  for (int i = e0 + tid; i < e1; i += 256)
    atomicAdd(&lcnt[((unsigned)bb[i].x) >> 24], 1);
  __syncthreads();
  if (tid == 0) {
    int s = e0;
    for (int i = 0; i < nd; i++) { loff[i] = s; s += lcnt[i]; }
  }
  __syncthreads();
  for (int i = tid; i < nd; i += 256) {
    off[d0 + i] = loff[i];
    cnt[d0 + i] = lcnt[i];
  }
  __syncthreads();
  for (int i = tid; i < nd; i += 256) lcnt[i] = loff[i];  // reuse as cursors
  __syncthreads();
  for (int i = e0 + tid; i < e1; i += 256) {
    int2 e = bb[i];
    int pos = atomicAdd(&lcnt[((unsigned)e.x) >> 24], 1);
    edges[pos] = make_int2(e.x & 0xFFFFFF, e.y);
  }
}

// ---------------- gather-aggregate: one dst per wave, 64 lanes x 8B ----------
// unroll-8: 8 independent 512B row loads in flight per wave; edge reads are
// wave-uniform -> scalar loads.
__device__ inline void acc4(float& a0, float& a1, float& a2, float& a3,
                            uint2 v, float w) {
  a0 = fmaf(w, __uint_as_float(v.x << 16), a0);
  a1 = fmaf(w, __uint_as_float(v.x & 0xffff0000u), a1);
  a2 = fmaf(w, __uint_as_float(v.y << 16), a2);
  a3 = fmaf(w, __uint_as_float(v.y & 0xffff0000u), a3);
}

__global__ __launch_bounds__(256) void gather_kernel(const uint2* __restrict__ x8,
                                                     const int2* __restrict__ edges,
                                                     const int* __restrict__ off,
                                                     const int* __restrict__ cnt,
                                                     uint2* __restrict__ agg8, int N) {
  int d = blockIdx.x * 4 + (threadIdx.x >> 6);
  if (d >= N) return;
  int c = threadIdx.x & 63;
  int start = off[d], n = cnt[d];
  float a0 = 0.f, a1 = 0.f, a2 = 0.f, a3 = 0.f;
  int t = 0;
  for (; t + 8 <= n; t += 8) {
    int2 e0 = edges[start + t + 0];
    int2 e1 = edges[start + t + 1];
    int2 e2 = edges[start + t + 2];
    int2 e3 = edges[start + t + 3];
    int2 e4 = edges[start + t + 4];
    int2 e5 = edges[start + t + 5];
    int2 e6 = edges[start + t + 6];
    int2 e7 = edges[start + t + 7];
    uint2 v0 = x8[(size_t)e0.x * 64 + c];
    uint2 v1 = x8[(size_t)e1.x * 64 + c];
    uint2 v2 = x8[(size_t)e2.x * 64 + c];
    uint2 v3 = x8[(size_t)e3.x * 64 + c];
    uint2 v4 = x8[(size_t)e4.x * 64 + c];
    uint2 v5 = x8[(size_t)e5.x * 64 + c];
    uint2 v6 = x8[(size_t)e6.x * 64 + c];
    uint2 v7 = x8[(size_t)e7.x * 64 + c];
    acc4(a0, a1, a2, a3, v0, __int_as_float(e0.y));
    acc4(a0, a1, a2, a3, v1, __int_as_float(e1.y));
    acc4(a0, a1, a2, a3, v2, __int_as_float(e2.y));
    acc4(a0, a1, a2, a3, v3, __int_as_float(e3.y));
    acc4(a0, a1, a2, a3, v4, __int_as_float(e4.y));
    acc4(a0, a1, a2, a3, v5, __int_as_float(e5.y));
    acc4(a0, a1, a2, a3, v6, __int_as_float(e6.y));
    acc4(a0, a1, a2, a3, v7, __int_as_float(e7.y));
  }
  for (; t < n; t++) {
    int2 e0 = edges[start + t];
    uint2 v0 = x8[(size_t)e0.x * 64 + c];
    acc4(a0, a1, a2, a3, v0, __int_as_float(e0.y));
  }
  agg8[(size_t)d * 64 + c] = make_uint2(bfpack(a0, a1), bfpack(a2, a3));
}

// ---------------- MFMA GEMM: out(fp32) = agg(bf16) @ (hamT_hi+hamT_lo)^T ------
// 128x256 (full-width) tile; 8 waves (2m x 4n); A in LDS (swizzled);
// B fragments straight from global (L2-hot, 256 KB); BN sum/sumsq fused.
__global__ __launch_bounds__(512) void mfma_gemm(const uint4* __restrict__ aggh,
                                                 const unsigned short* __restrict__ hamT_hi,
                                                 const unsigned short* __restrict__ hamT_lo,
                                                 float* __restrict__ bnsum,
                                                 float* __restrict__ out, int N) {
  __shared__ __align__(16) unsigned short Al[128 * 256];  // 64 KB
  __shared__ float csum[256], csq[256];
  const int tid = threadIdx.x;
  const int row0 = blockIdx.x * 128;
  const int lane = tid & 63, wv = tid >> 6;
  const int wm = wv >> 2, wn = wv & 3;   // wave tile: 64 rows x 64 cols

  if (tid < 256) { csum[tid] = 0.f; csq[tid] = 0.f; }

  // stage A: 128 rows x 256 k (one-shot), zero-fill OOB rows
  #pragma unroll
  for (int it = 0; it < 8; it++) {
    int cidx = it * 512 + tid;
    int row = cidx >> 5, c16 = cidx & 31;
    int rg = row0 + row;
    uint4 v = make_uint4(0u, 0u, 0u, 0u);
    if (rg < N) v = aggh[(size_t)rg * 32 + c16];
    *(uint4*)((char*)Al + row * 512 + ((c16 * 16) ^ ((row & 7) << 4))) = v;
  }
  __syncthreads();

  f32x4 acc[4][4];
  #pragma unroll
  for (int m = 0; m < 4; m++)
    #pragma unroll
    for (int n = 0; n < 4; n++) acc[m][n] = (f32x4)0.f;

  const char* bh = (const char*)hamT_hi;
  const char* bl = (const char*)hamT_lo;
  #pragma unroll
  for (int kk = 0; kk < 8; kk++) {
    const int kbyte = (lane >> 4) * 16 + kk * 64;
    short8 af[4];
    #pragma unroll
    for (int m = 0; m < 4; m++) {
      int row = wm * 64 + m * 16 + (lane & 15);
      af[m] = *(const short8*)((const char*)Al + row * 512 + (kbyte ^ ((row & 7) << 4)));
    }
    #pragma unroll
    for (int n = 0; n < 4; n++) {
      int colg = wn * 64 + n * 16 + (lane & 15);
      size_t boff = (size_t)colg * 512 + kbyte;
      short8 bhv = *(const short8*)(bh + boff);
      short8 blv = *(const short8*)(bl + boff);
      #pragma unroll
      for (int m = 0; m < 4; m++)
        acc[m][n] = __builtin_amdgcn_mfma_f32_16x16x32_bf16(af[m], bhv, acc[m][n], 0, 0, 0);
      #pragma unroll
      for (int m = 0; m < 4; m++)
        acc[m][n] = __builtin_amdgcn_mfma_f32_16x16x32_bf16(af[m], blv, acc[m][n], 0, 0, 0);
    }
  }

  // epilogue: write fp32 out + fused BN partials (OOB rows are exact zeros)
  #pragma unroll
  for (int n = 0; n < 4; n++) {
    int colg = wn * 64 + n * 16 + (lane & 15);
    float s = 0.f, q = 0.f;
    #pragma unroll
    for (int m = 0; m < 4; m++) {
      int rgb = row0 + wm * 64 + m * 16 + (lane >> 4) * 4;
      #pragma unroll
      for (int r = 0; r < 4; r++) {
        float v = acc[m][n][r];
        s += v; q = fmaf(v, v, q);
        int rg = rgb + r;
        if (rg < N) out[(size_t)rg * 256 + colg] = v;
      }
    }
    s += __shfl_xor(s, 16); s += __shfl_xor(s, 32);
    q += __shfl_xor(q, 16); q += __shfl_xor(q, 32);
    if (lane < 16) {
      atomicAdd(&csum[wn * 64 + n * 16 + lane], s);
      atomicAdd(&csq [wn * 64 + n * 16 + lane], q);
    }
  }
  __syncthreads();
  if (tid < 256) {
    atomicAdd(&bnsum[tid], csum[tid]);
    atomicAdd(&bnsum[256 + tid], csq[tid]);
  }
}

// ---------------- BN apply + tanh (bnscale folded in) ----------------
__global__ __launch_bounds__(256) void final_kernel(float* __restrict__ out,
                                                    const float* __restrict__ bnsum,
                                                    const float* __restrict__ gamma,
                                                    const float* __restrict__ beta,
                                                    float invN, size_t total4) {
  size_t idx = (size_t)blockIdx.x * 256 + threadIdx.x;
  size_t stride = (size_t)gridDim.x * 256;
  // column set of this thread is constant across grid-stride iterations
  int c0 = (int)((idx * 4) & 255);
  float sc[4], ofs[4];
  #pragma unroll
  for (int j = 0; j < 4; j++) {
    float mean = bnsum[c0 + j] * invN;
    float var  = bnsum[256 + c0 + j] * invN - mean * mean;
    float s = rsqrtf(var + 1e-5f) * gamma[c0 + j];
    sc[j] = s;
    ofs[j] = beta[c0 + j] - mean * s;
  }
  float4* out4 = (float4*)out;
  for (size_t i = idx; i < total4; i += stride) {
    float4 v = out4[i];
    v.x = tanhf(fmaf(v.x, sc[0], ofs[0]));
    v.y = tanhf(fmaf(v.y, sc[1], ofs[1]));
    v.z = tanhf(fmaf(v.z, sc[2], ofs[2]));
    v.w = tanhf(fmaf(v.w, sc[3], ofs[3]));
    out4[i] = v;
  }
}

// ---------------- launch ----------------
extern "C" void kernel_launch(void* const* d_in, const int* in_sizes, int n_in,
                              void* d_out, int out_size, void* d_ws, size_t ws_size,
                              hipStream_t stream) {
  const float* x      = (const float*)d_in[0];
  const float* weight = (const float*)d_in[1];
  const float* gamma  = (const float*)d_in[2];
  const float* beta   = (const float*)d_in[3];
  const float* ew     = (const float*)d_in[4];
  const int*   esrc   = (const int*)d_in[5];
  const int*   edst   = (const int*)d_in[6];
  const int N = in_sizes[0] / 256;
  const int E = in_sizes[4];
  float* out = (float*)d_out;

  char* p = (char*)d_ws;
  auto alloc = [&](size_t bytes) {
    char* q = p;
    p += (bytes + 255) & ~(size_t)255;
    return q;
  };
  unsigned short* hamT_hi = (unsigned short*)alloc(65536 * 2);
  unsigned short* hamT_lo = (unsigned short*)alloc(65536 * 2);
  int*   binTot    = (int*)alloc(NB * 4);
  int*   binStart  = (int*)alloc((NB + 1) * 4);
  int*   binCursor = (int*)alloc(NB * 4);
  int*   cnt       = (int*)alloc((size_t)N * 4);
  int*   off       = (int*)alloc((size_t)N * 4);
  int2*  bb        = (int2*)alloc((size_t)E * 8);
  int2*  edges     = (int2*)alloc((size_t)E * 8);
  uint2* xh        = (uint2*)alloc((size_t)N * 256 * 2);
  uint4* aggh      = (uint4*)alloc((size_t)N * 256 * 2);
  float* bnsum     = (float*)alloc(512 * 4);

  hipMemsetAsync(binTot, 0, NB * 4, stream);
  hipMemsetAsync(bnsum, 0, 512 * 4, stream);

  const int gridE = (E + CHUNK - 1) / CHUNK;
  const int rowBlocks = (N + 127) / 128;

  hamT_kernel<<<256, 256, 0, stream>>>(weight, hamT_hi, hamT_lo);
  cvt_kernel<<<2048, 256, 0, stream>>>((const float4*)x, xh, (size_t)N * 64);
  binhist_kernel<<<gridE, 256, 0, stream>>>(edst, binTot, E, N);
  binscan_kernel<<<1, 512, 0, stream>>>(binTot, binStart, binCursor, E);
  bin_scatter<<<gridE, 256, 0, stream>>>(esrc, edst, ew, binCursor, bb, E, N);
  bin_place<<<NB, 256, 0, stream>>>(bb, binStart, off, cnt, edges, N);
  gather_kernel<<<(N + 3) / 4, 256, 0, stream>>>((const uint2*)xh, edges, off, cnt,
                                                 (uint2*)aggh, N);
  mfma_gemm<<<rowBlocks, 512, 0, stream>>>(aggh, hamT_hi, hamT_lo, bnsum, out, N);
  final_kernel<<<2048, 256, 0, stream>>>(out, bnsum, gamma, beta, 1.f / (float)N,
                                         (size_t)N * 64);
}